// Round 5
// baseline (318.790 us; speedup 1.0000x reference)
//
#include <hip/hip_runtime.h>
#include <hip/hip_bf16.h>
#include <math.h>

typedef __bf16 bf16x8 __attribute__((ext_vector_type(8)));
typedef float  f32x4  __attribute__((ext_vector_type(4)));
typedef short  s16x4  __attribute__((ext_vector_type(4)));
typedef unsigned int u32x2 __attribute__((ext_vector_type(2)));

#define B_   4
#define N_   2048
#define C_   512
#define H_   8
#define DH_  64
#define HID_ 2048
#define MTOK 8192
#define LOG2E 1.4426950408889634f

__device__ inline void gld_lds16(const void* g, void* l) {
  __builtin_amdgcn_global_load_lds((const __attribute__((address_space(1))) void*)g,
                                   (__attribute__((address_space(3))) void*)l,
                                   16, 0, 0);
}

// round-half-up f32->bf16 pack (P>=0, no NaN): 5 VALU per pair
__device__ inline unsigned pack2_bf16(float a, float b) {
  unsigned ua = __builtin_bit_cast(unsigned, a);
  unsigned ub = __builtin_bit_cast(unsigned, b);
  return ((ua + 0x8000u) >> 16) | ((ub + 0x8000u) & 0xFFFF0000u);
}

// ---------------- C = A[M,K] * B[N,K]^T, 1-barrier double-buffered K-loop -----
// EPI 0: qkv split-store: q,k -> [b,h,n,d]; v -> V^T [b,h,d,n]  (bf16)
// EPI 1: fout = acc + bias[col] + resid  (fp32)
// EPI 2: bout = gelu(acc + bias[col])    (bf16)
template<int EPI, int BN>
__global__ __launch_bounds__(256) void gemm_bt(
    const __bf16* __restrict__ A, const __bf16* __restrict__ Bw,
    int M, int N, int K,
    const float* __restrict__ bias, const float* __restrict__ resid,
    float* __restrict__ fout, __bf16* __restrict__ bout,
    __bf16* __restrict__ qo, __bf16* __restrict__ ko, __bf16* __restrict__ vo)
{
  constexpr int MT = (BN == 128) ? 4 : 2;
  __shared__ __align__(16) __bf16 a_lds[2][128 * 32];
  __shared__ __align__(16) __bf16 b_lds[2][BN * 32];
  const int tid  = threadIdx.x;
  const int wave = tid >> 6, lane = tid & 63;
  const int quad = lane >> 4, l16 = lane & 15;
  const int bm = blockIdx.x * 128, bn = blockIdx.y * BN;
  const int wr = (BN == 128) ? (wave >> 1) * 64 : wave * 32;
  const int wc = (BN == 128) ? (wave & 1) * 64 : 0;
  const int rw = lane >> 2;
  const int c4 = lane & 3;

  const f32x4 fzero = {0.f, 0.f, 0.f, 0.f};
  f32x4 acc[MT][4];
  #pragma unroll
  for (int i = 0; i < MT; ++i)
    #pragma unroll
    for (int j = 0; j < 4; ++j) acc[i][j] = fzero;

  auto stage = [&](int buf, int k0) {
    #pragma unroll
    for (int j = 0; j < 2; ++j) {
      const int rbase = wave * 32 + j * 16;
      gld_lds16(A + (size_t)(bm + rbase + rw) * K + k0 + c4 * 8, &a_lds[buf][rbase * 32]);
    }
    if constexpr (BN == 128) {
      #pragma unroll
      for (int j = 0; j < 2; ++j) {
        const int rbase = wave * 32 + j * 16;
        gld_lds16(Bw + (size_t)(bn + rbase + rw) * K + k0 + c4 * 8, &b_lds[buf][rbase * 32]);
      }
    } else {
      gld_lds16(Bw + (size_t)(bn + wave * 16 + rw) * K + k0 + c4 * 8, &b_lds[buf][wave * 512]);
    }
  };

  const int nk = K >> 5;
  stage(0, 0);
  for (int ki = 0; ki < nk; ++ki) {
    const int cur = ki & 1;
    __syncthreads();
    if (ki + 1 < nk) stage(cur ^ 1, (ki + 1) << 5);
    bf16x8 af[MT], bf[4];
    #pragma unroll
    for (int t = 0; t < MT; ++t)
      af[t] = *(const bf16x8*)&a_lds[cur][(wr + t * 16 + l16) * 32 + quad * 8];
    #pragma unroll
    for (int t = 0; t < 4; ++t)
      bf[t] = *(const bf16x8*)&b_lds[cur][(wc + t * 16 + l16) * 32 + quad * 8];
    #pragma unroll
    for (int mt = 0; mt < MT; ++mt)
      #pragma unroll
      for (int nt = 0; nt < 4; ++nt)
        acc[mt][nt] = __builtin_amdgcn_mfma_f32_16x16x32_bf16(af[mt], bf[nt], acc[mt][nt], 0, 0, 0);
  }

  #pragma unroll
  for (int mt = 0; mt < MT; ++mt) {
    #pragma unroll
    for (int nt = 0; nt < 4; ++nt) {
      #pragma unroll
      for (int r = 0; r < 4; ++r) {
        const int row = bm + wr + mt * 16 + quad * 4 + r;
        const int col = bn + wc + nt * 16 + l16;
        float v = acc[mt][nt][r];
        if (EPI == 0) {
          const int b = row >> 11, n = row & (N_ - 1);
          const int s = col >> 9, h = (col >> 6) & (H_ - 1), d = col & (DH_ - 1);
          if (s == 2) {
            vo[((((size_t)b * H_ + h) * DH_ + d) << 11) + n] = (__bf16)v;
          } else {
            __bf16* dst = s ? ko : qo;
            dst[((((size_t)b * H_ + h) * N_ + n) << 6) + d] = (__bf16)v;
          }
        } else if (EPI == 1) {
          const size_t idx = (size_t)row * N + col;
          fout[idx] = v + bias[col] + resid[idx];
        } else {
          const float xg = v + bias[col];
          bout[(size_t)row * N + col] =
              (__bf16)(0.5f * xg * (1.0f + erff(xg * 0.70710678118f)));
        }
      }
    }
  }
}

// ---------------- LayerNorm: fp32 in -> bf16 out, one wave per token ----------
__global__ __launch_bounds__(256) void ln_kernel(
    const float* __restrict__ x, const float* __restrict__ w,
    const float* __restrict__ b, __bf16* __restrict__ out)
{
  const int wave = threadIdx.x >> 6, lane = threadIdx.x & 63;
  const int tok  = blockIdx.x * 4 + wave;
  const float* xr = x + (size_t)tok * C_;
  float4 v0 = ((const float4*)xr)[lane];
  float4 v1 = ((const float4*)xr)[lane + 64];
  float s = v0.x + v0.y + v0.z + v0.w + v1.x + v1.y + v1.z + v1.w;
  float q = v0.x*v0.x + v0.y*v0.y + v0.z*v0.z + v0.w*v0.w
          + v1.x*v1.x + v1.y*v1.y + v1.z*v1.z + v1.w*v1.w;
  #pragma unroll
  for (int off = 32; off >= 1; off >>= 1) {
    s += __shfl_xor(s, off, 64);
    q += __shfl_xor(q, off, 64);
  }
  const float mu  = s * (1.0f / C_);
  const float var = q * (1.0f / C_) - mu * mu;
  const float rs  = rsqrtf(var + 1e-5f);
  float4 w0 = ((const float4*)w)[lane], w1 = ((const float4*)w)[lane + 64];
  float4 b0 = ((const float4*)b)[lane], b1 = ((const float4*)b)[lane + 64];
  __bf16* orow = out + (size_t)tok * C_;
  const int c0 = lane * 4;
  orow[c0 + 0]       = (__bf16)((v0.x - mu) * rs * w0.x + b0.x);
  orow[c0 + 1]       = (__bf16)((v0.y - mu) * rs * w0.y + b0.y);
  orow[c0 + 2]       = (__bf16)((v0.z - mu) * rs * w0.z + b0.z);
  orow[c0 + 3]       = (__bf16)((v0.w - mu) * rs * w0.w + b0.w);
  orow[256 + c0 + 0] = (__bf16)((v1.x - mu) * rs * w1.x + b1.x);
  orow[256 + c0 + 1] = (__bf16)((v1.y - mu) * rs * w1.y + b1.y);
  orow[256 + c0 + 2] = (__bf16)((v1.z - mu) * rs * w1.z + b1.z);
  orow[256 + c0 + 3] = (__bf16)((v1.w - mu) * rs * w1.w + b1.w);
}

// ---------------- flash attention v5: S^T trick, register-resident P ----------
// grid: (16 q-tiles, 32 bh). block 256 = 4 waves x 32 q (2 x 16-q column tiles).
// QK computed operand-swapped -> S^T in MFMA D-layout [key][q]; after exp2,
// P is directly the B-operand of a 16x16x16 PV MFMA (k = key). No P LDS trip.
// V^T staged with XOR-chunk swizzle for uniform-bank b64 A-operand reads.
// LDS 53.5 KB -> 3 blocks/CU. K double-buffered (prefetch issued at iter top,
// drained by the plain mid-iter __syncthreads -- R4's vmcnt(4) asm raced:
// compiler may interleave V/K global_load_lds issue order, so partial-drain
// counts are unsound at HIP level).
__global__ __launch_bounds__(256, 3) void flash_kernel(
    const __bf16* __restrict__ qb, const __bf16* __restrict__ kb,
    const __bf16* __restrict__ vtg, const float* __restrict__ rpb,
    __bf16* __restrict__ outb)
{
  __shared__ __align__(16) __bf16 kbufs[2][8192];   // [ks][128 key][32 d]
  __shared__ __align__(16) __bf16 vbuf[8192];       // [4 ks2][64 d][32 key] chunk-swizzled
  __shared__ __bf16 bias_local[2176];               // pre-scaled by log2e
  const int tid  = threadIdx.x;
  const int wave = tid >> 6, lane = tid & 63;
  const int quad = lane >> 4, l16 = lane & 15;
  const int bh = blockIdx.y, h = bh & (H_ - 1);
  const int q0 = blockIdx.x * 128;
  const int boff = 1920 - q0;
  const float SCL = 0.125f * LOG2E;

  for (int i = tid; i < 2175; i += 256)
    bias_local[i] = (__bf16)(rpb[(size_t)(i + boff) * H_ + h] * LOG2E);

  const __bf16* qptr = qb  + (size_t)bh * N_ * DH_;
  const __bf16* kptr = kb  + (size_t)bh * N_ * DH_;
  const __bf16* vtp  = vtg + (size_t)bh * N_ * DH_;

  // Q fragments (B-operand of QK): lane l16 -> q row, k = ks*32 + quad*8..
  bf16x8 qf[2][2];
  #pragma unroll
  for (int mt = 0; mt < 2; ++mt)
    #pragma unroll
    for (int ks = 0; ks < 2; ++ks)
      qf[mt][ks] = *(const bf16x8*)(qptr +
          (size_t)(q0 + wave * 32 + mt * 16 + l16) * DH_ + ks * 32 + quad * 8);

  float l_i[2] = {0.f, 0.f};
  f32x4 o[2][4];
  const f32x4 fzero = {0.f, 0.f, 0.f, 0.f};
  #pragma unroll
  for (int mt = 0; mt < 2; ++mt)
    #pragma unroll
    for (int dt = 0; dt < 4; ++dt) o[mt][dt] = fzero;

  const int slr = lane >> 2;
  const int slc = lane & 3;

  auto stageK = [&](int buf, int kcn) {
    #pragma unroll
    for (int j = 0; j < 4; ++j) {
      const int idx = wave * 4 + j;
      const int ks = idx & 1, g = idx >> 1;
      gld_lds16(kptr + (size_t)(kcn + g * 16 + slr) * DH_ + ks * 32 + slc * 8,
                &kbufs[buf][ks * 4096 + g * 512]);
    }
  };
  // source-chunk XOR swizzle: vbuf[ks2][d][chunk] holds global chunk (chunk^(d&3))
  auto stageV = [&](int kcn) {
    #pragma unroll
    for (int j = 0; j < 4; ++j) {
      const int idx = wave * 4 + j;
      const int ks2 = idx & 3, g = idx >> 2;
      gld_lds16(vtp + (size_t)(g * 16 + slr) * N_ + kcn + ks2 * 32 + (slc ^ (slr & 3)) * 8,
                &vbuf[ks2 * 2048 + g * 512]);
    }
  };

  stageK(0, 0);
  for (int it = 0; it < 16; ++it) {
    const int cur = it & 1;
    const int kc = it << 7;
    __syncthreads();                 // K[cur] + V drained; prior PV reads of vbuf done
    stageV(kc);
    if (it < 15) stageK(cur ^ 1, kc + 128);

    // ---- QK^T, operand-swapped: s[mt][ct] = S^T block [key=ct*16+quad*4+r][q=l16]
    f32x4 s[2][8];
    #pragma unroll
    for (int ct = 0; ct < 8; ++ct) {
      const bf16x8 kf0 = *(const bf16x8*)&kbufs[cur][(ct * 16 + l16) * 32 + quad * 8];
      const bf16x8 kf1 = *(const bf16x8*)&kbufs[cur][4096 + (ct * 16 + l16) * 32 + quad * 8];
      s[0][ct] = __builtin_amdgcn_mfma_f32_16x16x32_bf16(kf0, qf[0][0], fzero,    0, 0, 0);
      s[0][ct] = __builtin_amdgcn_mfma_f32_16x16x32_bf16(kf1, qf[0][1], s[0][ct], 0, 0, 0);
      s[1][ct] = __builtin_amdgcn_mfma_f32_16x16x32_bf16(kf0, qf[1][0], fzero,    0, 0, 0);
      s[1][ct] = __builtin_amdgcn_mfma_f32_16x16x32_bf16(kf1, qf[1][1], s[1][ct], 0, 0, 0);
    }

    // ---- no-max softmax; pack P into 16x16x16 B-operands (registers)
    unsigned pk[2][8][2];
    #pragma unroll
    for (int mt = 0; mt < 2; ++mt) {
      const __bf16* bp = &bias_local[kc + quad * 4 + 127 - wave * 32 - mt * 16 - l16];
      float lp = 0.f;
      #pragma unroll
      for (int ct = 0; ct < 8; ++ct) {
        float p[4];
        #pragma unroll
        for (int r = 0; r < 4; ++r) {
          const float sv = s[mt][ct][r] * SCL + (float)bp[ct * 16 + r];
          p[r] = __builtin_amdgcn_exp2f(sv);
          lp += p[r];
        }
        pk[mt][ct][0] = pack2_bf16(p[0], p[1]);
        pk[mt][ct][1] = pack2_bf16(p[2], p[3]);
      }
      l_i[mt] += lp;
    }

    __syncthreads();                 // V (and K prefetch) visible

    // ---- PV: o^T[d][q] += V^T-frag x P-frag  (16x16x16, k=key)
    #pragma unroll
    for (int ct = 0; ct < 8; ++ct) {
      const int chsw = (((ct & 1) * 2 + (quad >> 1)) ^ (l16 & 3));
      const int vbase = (ct >> 1) * 2048 + l16 * 32 + chsw * 8 + (quad & 1) * 4;
      const s16x4 pf0 = __builtin_bit_cast(s16x4, u32x2{pk[0][ct][0], pk[0][ct][1]});
      const s16x4 pf1 = __builtin_bit_cast(s16x4, u32x2{pk[1][ct][0], pk[1][ct][1]});
      #pragma unroll
      for (int dt = 0; dt < 4; ++dt) {
        const s16x4 vf = *(const s16x4*)&vbuf[vbase + dt * 512];
        o[0][dt] = __builtin_amdgcn_mfma_f32_16x16x16bf16_1k(vf, pf0, o[0][dt], 0, 0, 0);
        o[1][dt] = __builtin_amdgcn_mfma_f32_16x16x16bf16_1k(vf, pf1, o[1][dt], 0, 0, 0);
      }
    }
  }

  // ---- epilogue: l reduce over quads, normalize, b64 stores
  const int b = bh >> 3;
  #pragma unroll
  for (int mt = 0; mt < 2; ++mt) {
    float l = l_i[mt];
    l += __shfl_xor(l, 16, 64);
    l += __shfl_xor(l, 32, 64);
    const float inv = 1.0f / l;
    const int qg = q0 + wave * 32 + mt * 16 + l16;
    __bf16* orow = outb + ((size_t)(b * N_ + qg)) * C_ + h * DH_ + quad * 4;
    #pragma unroll
    for (int dt = 0; dt < 4; ++dt) {
      u32x2 pkd;
      pkd.x = pack2_bf16(o[mt][dt][0] * inv, o[mt][dt][1] * inv);
      pkd.y = pack2_bf16(o[mt][dt][2] * inv, o[mt][dt][3] * inv);
      *(u32x2*)(orow + dt * 16) = pkd;
    }
  }
}

// ---------------- fp32 -> bf16 cast ------------------------------------------
__global__ void cast_kernel(const float* __restrict__ in, __bf16* __restrict__ out, int n) {
  const int i = blockIdx.x * 256 + threadIdx.x;
  if (i < n) out[i] = (__bf16)in[i];
}

extern "C" void kernel_launch(void* const* d_in, const int* in_sizes, int n_in,
                              void* d_out, int out_size, void* d_ws, size_t ws_size,
                              hipStream_t stream)
{
  const float* x      = (const float*)d_in[0];
  const float* qkv_w  = (const float*)d_in[1];
  const float* proj_w = (const float*)d_in[2];
  const float* proj_b = (const float*)d_in[3];
  const float* rpb    = (const float*)d_in[4];
  const float* n1w    = (const float*)d_in[5];
  const float* n1b    = (const float*)d_in[6];
  const float* n2w    = (const float*)d_in[7];
  const float* n2b    = (const float*)d_in[8];
  const float* fc1_w  = (const float*)d_in[9];
  const float* fc1_b  = (const float*)d_in[10];
  const float* fc2_w  = (const float*)d_in[11];
  const float* fc2_b  = (const float*)d_in[12];

  char* ws = (char*)d_ws;
  __bf16* hbuf = (__bf16*)(ws + 0);          // 8192*512  bf16
  __bf16* qbuf = (__bf16*)(ws + 8388608);    // [b,h,n,d]
  __bf16* kbuf = (__bf16*)(ws + 16777216);   // [b,h,n,d]
  __bf16* vbuf = (__bf16*)(ws + 25165824);   // V^T [b,h,d,n]
  __bf16* gelu = (__bf16*)(ws + 0);          // 8192*2048 bf16 (alias)
  __bf16* wq   = (__bf16*)(ws + 33554432);
  __bf16* wp   = (__bf16*)(ws + 35127296);
  __bf16* w1   = (__bf16*)(ws + 35651584);
  __bf16* w2   = (__bf16*)(ws + 37748736);
  __bf16* attn = (__bf16*)(ws + 39845888);   // 8192*512 bf16
  __bf16* h2in = attn;                       // alias
  float*  x1   = (float*)(ws + 48234496);    // 8192*512 fp32
  float*  outp = (float*)d_out;

  cast_kernel<<<(786432 + 255) / 256, 256, 0, stream>>>(qkv_w, wq, 786432);
  cast_kernel<<<(262144 + 255) / 256, 256, 0, stream>>>(proj_w, wp, 262144);
  cast_kernel<<<(1048576 + 255) / 256, 256, 0, stream>>>(fc1_w, w1, 1048576);
  cast_kernel<<<(1048576 + 255) / 256, 256, 0, stream>>>(fc2_w, w2, 1048576);

  ln_kernel<<<2048, 256, 0, stream>>>(x, n1w, n1b, hbuf);

  gemm_bt<0, 128><<<dim3(64, 12), 256, 0, stream>>>(hbuf, wq, MTOK, 1536, 512,
      nullptr, nullptr, nullptr, nullptr, qbuf, kbuf, vbuf);

  flash_kernel<<<dim3(16, 32), 256, 0, stream>>>(qbuf, kbuf, vbuf, rpb, attn);

  gemm_bt<1, 64><<<dim3(64, 8), 256, 0, stream>>>(attn, wp, MTOK, 512, 512,
      proj_b, x, x1, nullptr, nullptr, nullptr, nullptr);

  ln_kernel<<<2048, 256, 0, stream>>>(x1, n2w, n2b, h2in);

  gemm_bt<2, 128><<<dim3(64, 16), 256, 0, stream>>>(h2in, w1, MTOK, 2048, 512,
      fc1_b, nullptr, nullptr, gelu, nullptr, nullptr, nullptr);

  gemm_bt<1, 64><<<dim3(64, 8), 256, 0, stream>>>(gelu, w2, MTOK, 512, 2048,
      fc2_b, x1, outp, nullptr, nullptr, nullptr, nullptr);
}

// Round 6
// 289.410 us; speedup vs baseline: 1.1015x; 1.1015x over previous
//
#include <hip/hip_runtime.h>
#include <hip/hip_bf16.h>
#include <math.h>

typedef __bf16 bf16x8 __attribute__((ext_vector_type(8)));
typedef float  f32x4  __attribute__((ext_vector_type(4)));
typedef short  s16x4  __attribute__((ext_vector_type(4)));
typedef unsigned int u32x2 __attribute__((ext_vector_type(2)));

#define B_   4
#define N_   2048
#define C_   512
#define H_   8
#define DH_  64
#define HID_ 2048
#define MTOK 8192
#define LOG2E 1.4426950408889634f
#define QSCALE 0.18033688011112042f   // 0.125 * log2(e), folded into Q store

__device__ inline void gld_lds16(const void* g, void* l) {
  __builtin_amdgcn_global_load_lds((const __attribute__((address_space(1))) void*)g,
                                   (__attribute__((address_space(3))) void*)l,
                                   16, 0, 0);
}

// round-half-up f32->bf16 pack (operands >=0 or normal, no NaN)
__device__ inline unsigned pack2_bf16(float a, float b) {
  unsigned ua = __builtin_bit_cast(unsigned, a);
  unsigned ub = __builtin_bit_cast(unsigned, b);
  return ((ua + 0x8000u) >> 16) | ((ub + 0x8000u) & 0xFFFF0000u);
}

// ---------------- C = A[M,K] * B[N,K]^T, 1-barrier double-buffered K-loop -----
// EPI 0: qkv split-store: q (x QSCALE), k -> [b,h,n,d]; v -> V^T [b,h,d,n]
// EPI 1: fout = acc + bias[col] + resid  (fp32)
// EPI 2: bout = gelu(acc + bias[col])    (bf16)
template<int EPI, int BN>
__global__ __launch_bounds__(256) void gemm_bt(
    const __bf16* __restrict__ A, const __bf16* __restrict__ Bw,
    int M, int N, int K,
    const float* __restrict__ bias, const float* __restrict__ resid,
    float* __restrict__ fout, __bf16* __restrict__ bout,
    __bf16* __restrict__ qo, __bf16* __restrict__ ko, __bf16* __restrict__ vo)
{
  constexpr int MT = (BN == 128) ? 4 : 2;
  __shared__ __align__(16) __bf16 a_lds[2][128 * 32];
  __shared__ __align__(16) __bf16 b_lds[2][BN * 32];
  const int tid  = threadIdx.x;
  const int wave = tid >> 6, lane = tid & 63;
  const int quad = lane >> 4, l16 = lane & 15;
  const int bm = blockIdx.x * 128, bn = blockIdx.y * BN;
  const int wr = (BN == 128) ? (wave >> 1) * 64 : wave * 32;
  const int wc = (BN == 128) ? (wave & 1) * 64 : 0;
  const int rw = lane >> 2;
  const int c4 = lane & 3;

  const f32x4 fzero = {0.f, 0.f, 0.f, 0.f};
  f32x4 acc[MT][4];
  #pragma unroll
  for (int i = 0; i < MT; ++i)
    #pragma unroll
    for (int j = 0; j < 4; ++j) acc[i][j] = fzero;

  auto stage = [&](int buf, int k0) {
    #pragma unroll
    for (int j = 0; j < 2; ++j) {
      const int rbase = wave * 32 + j * 16;
      gld_lds16(A + (size_t)(bm + rbase + rw) * K + k0 + c4 * 8, &a_lds[buf][rbase * 32]);
    }
    if constexpr (BN == 128) {
      #pragma unroll
      for (int j = 0; j < 2; ++j) {
        const int rbase = wave * 32 + j * 16;
        gld_lds16(Bw + (size_t)(bn + rbase + rw) * K + k0 + c4 * 8, &b_lds[buf][rbase * 32]);
      }
    } else {
      gld_lds16(Bw + (size_t)(bn + wave * 16 + rw) * K + k0 + c4 * 8, &b_lds[buf][wave * 512]);
    }
  };

  const int nk = K >> 5;
  stage(0, 0);
  for (int ki = 0; ki < nk; ++ki) {
    const int cur = ki & 1;
    __syncthreads();
    if (ki + 1 < nk) stage(cur ^ 1, (ki + 1) << 5);
    bf16x8 af[MT], bf[4];
    #pragma unroll
    for (int t = 0; t < MT; ++t)
      af[t] = *(const bf16x8*)&a_lds[cur][(wr + t * 16 + l16) * 32 + quad * 8];
    #pragma unroll
    for (int t = 0; t < 4; ++t)
      bf[t] = *(const bf16x8*)&b_lds[cur][(wc + t * 16 + l16) * 32 + quad * 8];
    #pragma unroll
    for (int mt = 0; mt < MT; ++mt)
      #pragma unroll
      for (int nt = 0; nt < 4; ++nt)
        acc[mt][nt] = __builtin_amdgcn_mfma_f32_16x16x32_bf16(af[mt], bf[nt], acc[mt][nt], 0, 0, 0);
  }

  #pragma unroll
  for (int mt = 0; mt < MT; ++mt) {
    #pragma unroll
    for (int nt = 0; nt < 4; ++nt) {
      #pragma unroll
      for (int r = 0; r < 4; ++r) {
        const int row = bm + wr + mt * 16 + quad * 4 + r;
        const int col = bn + wc + nt * 16 + l16;
        float v = acc[mt][nt][r];
        if (EPI == 0) {
          const int b = row >> 11, n = row & (N_ - 1);
          const int s = col >> 9, h = (col >> 6) & (H_ - 1), d = col & (DH_ - 1);
          if (s == 2) {
            vo[((((size_t)b * H_ + h) * DH_ + d) << 11) + n] = (__bf16)v;
          } else if (s == 1) {
            ko[((((size_t)b * H_ + h) * N_ + n) << 6) + d] = (__bf16)v;
          } else {
            qo[((((size_t)b * H_ + h) * N_ + n) << 6) + d] = (__bf16)(v * QSCALE);
          }
        } else if (EPI == 1) {
          const size_t idx = (size_t)row * N + col;
          fout[idx] = v + bias[col] + resid[idx];
        } else {
          const float xg = v + bias[col];
          bout[(size_t)row * N + col] =
              (__bf16)(0.5f * xg * (1.0f + erff(xg * 0.70710678118f)));
        }
      }
    }
  }
}

// ---------------- LayerNorm: fp32 in -> bf16 out, one wave per token ----------
__global__ __launch_bounds__(256) void ln_kernel(
    const float* __restrict__ x, const float* __restrict__ w,
    const float* __restrict__ b, __bf16* __restrict__ out)
{
  const int wave = threadIdx.x >> 6, lane = threadIdx.x & 63;
  const int tok  = blockIdx.x * 4 + wave;
  const float* xr = x + (size_t)tok * C_;
  float4 v0 = ((const float4*)xr)[lane];
  float4 v1 = ((const float4*)xr)[lane + 64];
  float s = v0.x + v0.y + v0.z + v0.w + v1.x + v1.y + v1.z + v1.w;
  float q = v0.x*v0.x + v0.y*v0.y + v0.z*v0.z + v0.w*v0.w
          + v1.x*v1.x + v1.y*v1.y + v1.z*v1.z + v1.w*v1.w;
  #pragma unroll
  for (int off = 32; off >= 1; off >>= 1) {
    s += __shfl_xor(s, off, 64);
    q += __shfl_xor(q, off, 64);
  }
  const float mu  = s * (1.0f / C_);
  const float var = q * (1.0f / C_) - mu * mu;
  const float rs  = rsqrtf(var + 1e-5f);
  float4 w0 = ((const float4*)w)[lane], w1 = ((const float4*)w)[lane + 64];
  float4 b0 = ((const float4*)b)[lane], b1 = ((const float4*)b)[lane + 64];
  __bf16* orow = out + (size_t)tok * C_;
  const int c0 = lane * 4;
  orow[c0 + 0]       = (__bf16)((v0.x - mu) * rs * w0.x + b0.x);
  orow[c0 + 1]       = (__bf16)((v0.y - mu) * rs * w0.y + b0.y);
  orow[c0 + 2]       = (__bf16)((v0.z - mu) * rs * w0.z + b0.z);
  orow[c0 + 3]       = (__bf16)((v0.w - mu) * rs * w0.w + b0.w);
  orow[256 + c0 + 0] = (__bf16)((v1.x - mu) * rs * w1.x + b1.x);
  orow[256 + c0 + 1] = (__bf16)((v1.y - mu) * rs * w1.y + b1.y);
  orow[256 + c0 + 2] = (__bf16)((v1.z - mu) * rs * w1.z + b1.z);
  orow[256 + c0 + 3] = (__bf16)((v1.w - mu) * rs * w1.w + b1.w);
}

// ---------------- flash attention v6: 8 waves, aligned bias, swizzled V -------
// grid (16,32), block 512 = 8 waves x 16 q-rows. q-tile 128.
// S^T trick (K as A, Q as B) -> P in registers as PV B-operand (16x16x16).
// biasC: 2 shifted copies -> all bias reads are aligned ds_read_b32.
// V granule swizzle swz(d)=(d&3)^((d>>2)&3) -> conflict-free b64 PV reads.
// LDS 57.9 KB -> 2 blocks/CU (16 waves/CU).
__global__ __launch_bounds__(512, 4) void flash_kernel(
    const __bf16* __restrict__ qb, const __bf16* __restrict__ kb,
    const __bf16* __restrict__ vtg, const float* __restrict__ rpb,
    __bf16* __restrict__ outb)
{
  __shared__ __align__(16) __bf16 kbufs[2][8192];   // [ks][128 key][32 d]
  __shared__ __align__(16) __bf16 vbuf[8192];       // [4 ks2][64 d][32 key], granule-swizzled
  __shared__ __align__(16) __bf16 biasC[2][2192];   // copy a: bias[i - a], *LOG2E
  const int tid  = threadIdx.x;
  const int wave = tid >> 6, lane = tid & 63;
  const int quad = lane >> 4, l16 = lane & 15;
  const int bh = blockIdx.y, h = bh & (H_ - 1);
  const int q0 = blockIdx.x * 128;
  const int boff = 1920 - q0;

  #pragma unroll
  for (int a = 0; a < 2; ++a)
    for (int i = tid; i < 2192; i += 512) {
      int ridx = i - a + boff;
      ridx = ridx < 0 ? 0 : (ridx > 2 * N_ - 2 ? 2 * N_ - 2 : ridx);
      biasC[a][i] = (__bf16)(rpb[(size_t)ridx * H_ + h] * LOG2E);
    }

  const __bf16* qptr = qb  + (size_t)bh * N_ * DH_;
  const __bf16* kptr = kb  + (size_t)bh * N_ * DH_;
  const __bf16* vtp  = vtg + (size_t)bh * N_ * DH_;

  // Q fragments (B-operand of QK): q row = q0 + wave*16 + l16, k = ks*32 + quad*8..
  bf16x8 qf[2];
  #pragma unroll
  for (int ks = 0; ks < 2; ++ks)
    qf[ks] = *(const bf16x8*)(qptr +
        (size_t)(q0 + wave * 16 + l16) * DH_ + ks * 32 + quad * 8);

  float l_i = 0.f;
  f32x4 o[4];
  const f32x4 fzero = {0.f, 0.f, 0.f, 0.f};
  #pragma unroll
  for (int dt = 0; dt < 4; ++dt) o[dt] = fzero;

  const int slr = lane >> 2;                       // 0..15 d-row within group
  const int slc = lane & 3;                        // 16B granule
  const int vswz = (slr & 3) ^ ((slr >> 2) & 3);   // V source granule swizzle

  auto stageK = [&](int buf, int kcn) {
    #pragma unroll
    for (int j = 0; j < 2; ++j) {
      const int idx = wave * 2 + j;
      const int ks = idx & 1, g = idx >> 1;        // g = key group 0..7
      gld_lds16(kptr + (size_t)(kcn + g * 16 + slr) * DH_ + ks * 32 + slc * 8,
                &kbufs[buf][ks * 4096 + g * 512]);
    }
  };
  auto stageV = [&](int kcn) {
    #pragma unroll
    for (int j = 0; j < 2; ++j) {
      const int idx = wave * 2 + j;
      const int ks2 = idx & 3, gg = idx >> 2;      // gg = d group 0..3
      gld_lds16(vtp + (size_t)(gg * 16 + slr) * N_ + kcn + ks2 * 32 + (slc ^ vswz) * 8,
                &vbuf[ks2 * 2048 + gg * 512]);
    }
  };

  // per-lane bias copy select: a = bb & 1 (constant across iterations)
  const int bbase0 = quad * 4 + 127 - wave * 16 - l16;   // bb = kc + bbase0
  const int acp = bbase0 & 1;
  const __bf16* bcp = &biasC[acp][acp];                  // biasC[a][bb + a + ...]

  stageK(0, 0);
  for (int it = 0; it < 16; ++it) {
    const int cur = it & 1;
    const int kc = it << 7;
    __syncthreads();                 // K[cur] + V drained; prior PV reads done
    stageV(kc);
    if (it < 15) stageK(cur ^ 1, kc + 128);

    // ---- QK^T operand-swapped: s[ct] = S^T tile [key=ct*16+quad*4+r][q=l16]
    f32x4 s[8];
    #pragma unroll
    for (int ct = 0; ct < 8; ++ct) {
      const bf16x8 kf0 = *(const bf16x8*)&kbufs[cur][(ct * 16 + l16) * 32 + quad * 8];
      const bf16x8 kf1 = *(const bf16x8*)&kbufs[cur][4096 + (ct * 16 + l16) * 32 + quad * 8];
      s[ct] = __builtin_amdgcn_mfma_f32_16x16x32_bf16(kf0, qf[0], fzero, 0, 0, 0);
      s[ct] = __builtin_amdgcn_mfma_f32_16x16x32_bf16(kf1, qf[1], s[ct], 0, 0, 0);
    }

    // ---- no-max softmax with aligned b32 bias reads; pack P (B-operand regs)
    unsigned pk[8][2];
    float lp = 0.f;
    {
      const __bf16* bp = bcp + kc + bbase0;   // 4B-aligned by construction
      #pragma unroll
      for (int ct = 0; ct < 8; ++ct) {
        const unsigned w0 = *(const unsigned*)(bp + ct * 16);
        const unsigned w1 = *(const unsigned*)(bp + ct * 16 + 2);
        const float b0 = __builtin_bit_cast(float, w0 << 16);
        const float b1 = __builtin_bit_cast(float, w0 & 0xFFFF0000u);
        const float b2 = __builtin_bit_cast(float, w1 << 16);
        const float b3 = __builtin_bit_cast(float, w1 & 0xFFFF0000u);
        const float p0 = __builtin_amdgcn_exp2f(s[ct][0] + b0);
        const float p1 = __builtin_amdgcn_exp2f(s[ct][1] + b1);
        const float p2 = __builtin_amdgcn_exp2f(s[ct][2] + b2);
        const float p3 = __builtin_amdgcn_exp2f(s[ct][3] + b3);
        lp += (p0 + p1) + (p2 + p3);
        pk[ct][0] = pack2_bf16(p0, p1);
        pk[ct][1] = pack2_bf16(p2, p3);
      }
    }
    l_i += lp;

    __syncthreads();                 // V (and K prefetch) visible

    // ---- PV: o^T[d][q] += V^T-frag x P-frag (16x16x16, k = key)
    #pragma unroll
    for (int ct = 0; ct < 8; ++ct) {
      const int gran = ((ct & 1) * 2 + (quad >> 1)) ^ ((l16 & 3) ^ ((l16 >> 2) & 3));
      const int vbase = (ct >> 1) * 2048 + l16 * 32 + gran * 8 + (quad & 1) * 4;
      const s16x4 pf = __builtin_bit_cast(s16x4, u32x2{pk[ct][0], pk[ct][1]});
      #pragma unroll
      for (int dt = 0; dt < 4; ++dt) {
        const s16x4 vf = *(const s16x4*)&vbuf[vbase + dt * 512];
        o[dt] = __builtin_amdgcn_mfma_f32_16x16x16bf16_1k(vf, pf, o[dt], 0, 0, 0);
      }
    }
  }

  // ---- epilogue: l reduce over quads, normalize, b64 stores
  const int b = bh >> 3;
  float l = l_i;
  l += __shfl_xor(l, 16, 64);
  l += __shfl_xor(l, 32, 64);
  const float inv = 1.0f / l;
  const int qg = q0 + wave * 16 + l16;
  __bf16* orow = outb + ((size_t)(b * N_ + qg)) * C_ + h * DH_ + quad * 4;
  #pragma unroll
  for (int dt = 0; dt < 4; ++dt) {
    u32x2 pkd;
    pkd.x = pack2_bf16(o[dt][0] * inv, o[dt][1] * inv);
    pkd.y = pack2_bf16(o[dt][2] * inv, o[dt][3] * inv);
    *(u32x2*)(orow + dt * 16) = pkd;
  }
}

// ---------------- fp32 -> bf16 cast ------------------------------------------
__global__ void cast_kernel(const float* __restrict__ in, __bf16* __restrict__ out, int n) {
  const int i = blockIdx.x * 256 + threadIdx.x;
  if (i < n) out[i] = (__bf16)in[i];
}

extern "C" void kernel_launch(void* const* d_in, const int* in_sizes, int n_in,
                              void* d_out, int out_size, void* d_ws, size_t ws_size,
                              hipStream_t stream)
{
  const float* x      = (const float*)d_in[0];
  const float* qkv_w  = (const float*)d_in[1];
  const float* proj_w = (const float*)d_in[2];
  const float* proj_b = (const float*)d_in[3];
  const float* rpb    = (const float*)d_in[4];
  const float* n1w    = (const float*)d_in[5];
  const float* n1b    = (const float*)d_in[6];
  const float* n2w    = (const float*)d_in[7];
  const float* n2b    = (const float*)d_in[8];
  const float* fc1_w  = (const float*)d_in[9];
  const float* fc1_b  = (const float*)d_in[10];
  const float* fc2_w  = (const float*)d_in[11];
  const float* fc2_b  = (const float*)d_in[12];

  char* ws = (char*)d_ws;
  __bf16* hbuf = (__bf16*)(ws + 0);          // 8192*512  bf16
  __bf16* qbuf = (__bf16*)(ws + 8388608);    // [b,h,n,d] (pre-scaled by QSCALE)
  __bf16* kbuf = (__bf16*)(ws + 16777216);   // [b,h,n,d]
  __bf16* vbuf = (__bf16*)(ws + 25165824);   // V^T [b,h,d,n]
  __bf16* gelu = (__bf16*)(ws + 0);          // 8192*2048 bf16 (alias)
  __bf16* wq   = (__bf16*)(ws + 33554432);
  __bf16* wp   = (__bf16*)(ws + 35127296);
  __bf16* w1   = (__bf16*)(ws + 35651584);
  __bf16* w2   = (__bf16*)(ws + 37748736);
  __bf16* attn = (__bf16*)(ws + 39845888);   // 8192*512 bf16
  __bf16* h2in = attn;                       // alias
  float*  x1   = (float*)(ws + 48234496);    // 8192*512 fp32
  float*  outp = (float*)d_out;

  cast_kernel<<<(786432 + 255) / 256, 256, 0, stream>>>(qkv_w, wq, 786432);
  cast_kernel<<<(262144 + 255) / 256, 256, 0, stream>>>(proj_w, wp, 262144);
  cast_kernel<<<(1048576 + 255) / 256, 256, 0, stream>>>(fc1_w, w1, 1048576);
  cast_kernel<<<(1048576 + 255) / 256, 256, 0, stream>>>(fc2_w, w2, 1048576);

  ln_kernel<<<2048, 256, 0, stream>>>(x, n1w, n1b, hbuf);

  gemm_bt<0, 128><<<dim3(64, 12), 256, 0, stream>>>(hbuf, wq, MTOK, 1536, 512,
      nullptr, nullptr, nullptr, nullptr, qbuf, kbuf, vbuf);

  flash_kernel<<<dim3(16, 32), 512, 0, stream>>>(qbuf, kbuf, vbuf, rpb, attn);

  gemm_bt<1, 64><<<dim3(64, 8), 256, 0, stream>>>(attn, wp, MTOK, 512, 512,
      proj_b, x, x1, nullptr, nullptr, nullptr, nullptr);

  ln_kernel<<<2048, 256, 0, stream>>>(x1, n2w, n2b, h2in);

  gemm_bt<2, 128><<<dim3(64, 16), 256, 0, stream>>>(h2in, w1, MTOK, 2048, 512,
      fc1_b, nullptr, nullptr, gelu, nullptr, nullptr, nullptr);

  gemm_bt<1, 64><<<dim3(64, 8), 256, 0, stream>>>(gelu, w2, MTOK, 512, 2048,
      fc2_b, x1, outp, nullptr, nullptr, nullptr, nullptr);
}

// Round 7
// 271.934 us; speedup vs baseline: 1.1723x; 1.0643x over previous
//
#include <hip/hip_runtime.h>
#include <hip/hip_bf16.h>
#include <math.h>

typedef __bf16 bf16x8 __attribute__((ext_vector_type(8)));
typedef float  f32x4  __attribute__((ext_vector_type(4)));
typedef short  s16x4  __attribute__((ext_vector_type(4)));
typedef unsigned int u32x2 __attribute__((ext_vector_type(2)));

#define B_   4
#define N_   2048
#define C_   512
#define H_   8
#define DH_  64
#define HID_ 2048
#define MTOK 8192
#define LOG2E 1.4426950408889634f
#define QSCALE 0.18033688011112042f   // 0.125 * log2(e), folded into Q store

__device__ inline void gld_lds16(const void* g, void* l) {
  __builtin_amdgcn_global_load_lds((const __attribute__((address_space(1))) void*)g,
                                   (__attribute__((address_space(3))) void*)l,
                                   16, 0, 0);
}

__device__ inline unsigned pack2_bf16(float a, float b) {
  unsigned ua = __builtin_bit_cast(unsigned, a);
  unsigned ub = __builtin_bit_cast(unsigned, b);
  return ((ua + 0x8000u) >> 16) | ((ub + 0x8000u) & 0xFFFF0000u);
}

// ---------------- C = A[M,K] * B[N,K]^T, 256-thr 128x128, dbuf K-loop ---------
// EPI 0: qkv split-store: q (x QSCALE), k -> [b,h,n,d]; v -> V^T [b,h,d,n]
// EPI 2: bout = gelu(acc + bias[col])    (bf16)
template<int EPI>
__global__ __launch_bounds__(256) void gemm_bt(
    const __bf16* __restrict__ A, const __bf16* __restrict__ Bw,
    int M, int N, int K,
    const float* __restrict__ bias, __bf16* __restrict__ bout,
    __bf16* __restrict__ qo, __bf16* __restrict__ ko, __bf16* __restrict__ vo)
{
  __shared__ __align__(16) __bf16 a_lds[2][128 * 32];
  __shared__ __align__(16) __bf16 b_lds[2][128 * 32];
  const int tid  = threadIdx.x;
  const int wave = tid >> 6, lane = tid & 63;
  const int quad = lane >> 4, l16 = lane & 15;
  const int bm = blockIdx.x * 128, bn = blockIdx.y * 128;
  const int wr = (wave >> 1) * 64, wc = (wave & 1) * 64;
  const int rw = lane >> 2;
  const int c4 = lane & 3;

  const f32x4 fzero = {0.f, 0.f, 0.f, 0.f};
  f32x4 acc[4][4];
  #pragma unroll
  for (int i = 0; i < 4; ++i)
    #pragma unroll
    for (int j = 0; j < 4; ++j) acc[i][j] = fzero;

  auto stage = [&](int buf, int k0) {
    #pragma unroll
    for (int j = 0; j < 2; ++j) {
      const int rbase = wave * 32 + j * 16;
      gld_lds16(A + (size_t)(bm + rbase + rw) * K + k0 + c4 * 8, &a_lds[buf][rbase * 32]);
      gld_lds16(Bw + (size_t)(bn + rbase + rw) * K + k0 + c4 * 8, &b_lds[buf][rbase * 32]);
    }
  };

  const int nk = K >> 5;
  stage(0, 0);
  for (int ki = 0; ki < nk; ++ki) {
    const int cur = ki & 1;
    __syncthreads();
    if (ki + 1 < nk) stage(cur ^ 1, (ki + 1) << 5);
    bf16x8 af[4], bf[4];
    #pragma unroll
    for (int t = 0; t < 4; ++t)
      af[t] = *(const bf16x8*)&a_lds[cur][(wr + t * 16 + l16) * 32 + quad * 8];
    #pragma unroll
    for (int t = 0; t < 4; ++t)
      bf[t] = *(const bf16x8*)&b_lds[cur][(wc + t * 16 + l16) * 32 + quad * 8];
    #pragma unroll
    for (int mt = 0; mt < 4; ++mt)
      #pragma unroll
      for (int nt = 0; nt < 4; ++nt)
        acc[mt][nt] = __builtin_amdgcn_mfma_f32_16x16x32_bf16(af[mt], bf[nt], acc[mt][nt], 0, 0, 0);
  }

  #pragma unroll
  for (int mt = 0; mt < 4; ++mt) {
    #pragma unroll
    for (int nt = 0; nt < 4; ++nt) {
      #pragma unroll
      for (int r = 0; r < 4; ++r) {
        const int row = bm + wr + mt * 16 + quad * 4 + r;
        const int col = bn + wc + nt * 16 + l16;
        float v = acc[mt][nt][r];
        if (EPI == 0) {
          const int b = row >> 11, n = row & (N_ - 1);
          const int s = col >> 9, h = (col >> 6) & (H_ - 1), d = col & (DH_ - 1);
          if (s == 2) {
            vo[((((size_t)b * H_ + h) * DH_ + d) << 11) + n] = (__bf16)v;
          } else if (s == 1) {
            ko[((((size_t)b * H_ + h) * N_ + n) << 6) + d] = (__bf16)v;
          } else {
            qo[((((size_t)b * H_ + h) * N_ + n) << 6) + d] = (__bf16)(v * QSCALE);
          }
        } else {
          const float xg = v + bias[col];
          bout[(size_t)row * N + col] =
              (__bf16)(0.5f * xg * (1.0f + erff(xg * 0.70710678118f)));
        }
      }
    }
  }
}

// ---------------- C = A[M,K] * B[N,K]^T, 512-thr 128x64, fused resid (fp32) ---
// 8 waves in 4x2; each wave a 32x32 tile. grid (M/128, N/64).
__global__ __launch_bounds__(512) void gemm_bt8(
    const __bf16* __restrict__ A, const __bf16* __restrict__ Bw,
    int M, int N, int K,
    const float* __restrict__ bias, const float* __restrict__ resid,
    float* __restrict__ fout)
{
  __shared__ __align__(16) __bf16 a_lds[2][128 * 32];
  __shared__ __align__(16) __bf16 b_lds[2][64 * 32];
  const int tid  = threadIdx.x;
  const int wave = tid >> 6, lane = tid & 63;
  const int quad = lane >> 4, l16 = lane & 15;
  const int bm = blockIdx.x * 128, bn = blockIdx.y * 64;
  const int wr = (wave >> 1) * 32, wc = (wave & 1) * 32;
  const int rw = lane >> 2;
  const int c4 = lane & 3;

  const f32x4 fzero = {0.f, 0.f, 0.f, 0.f};
  f32x4 acc[2][2];
  #pragma unroll
  for (int i = 0; i < 2; ++i)
    #pragma unroll
    for (int j = 0; j < 2; ++j) acc[i][j] = fzero;

  auto stage = [&](int buf, int k0) {
    gld_lds16(A + (size_t)(bm + wave * 16 + rw) * K + k0 + c4 * 8, &a_lds[buf][wave * 512]);
    if (wave < 4)
      gld_lds16(Bw + (size_t)(bn + wave * 16 + rw) * K + k0 + c4 * 8, &b_lds[buf][wave * 512]);
  };

  const int nk = K >> 5;
  stage(0, 0);
  for (int ki = 0; ki < nk; ++ki) {
    const int cur = ki & 1;
    __syncthreads();
    if (ki + 1 < nk) stage(cur ^ 1, (ki + 1) << 5);
    bf16x8 af[2], bf[2];
    #pragma unroll
    for (int t = 0; t < 2; ++t)
      af[t] = *(const bf16x8*)&a_lds[cur][(wr + t * 16 + l16) * 32 + quad * 8];
    #pragma unroll
    for (int t = 0; t < 2; ++t)
      bf[t] = *(const bf16x8*)&b_lds[cur][(wc + t * 16 + l16) * 32 + quad * 8];
    #pragma unroll
    for (int mt = 0; mt < 2; ++mt)
      #pragma unroll
      for (int nt = 0; nt < 2; ++nt)
        acc[mt][nt] = __builtin_amdgcn_mfma_f32_16x16x32_bf16(af[mt], bf[nt], acc[mt][nt], 0, 0, 0);
  }

  #pragma unroll
  for (int mt = 0; mt < 2; ++mt) {
    #pragma unroll
    for (int nt = 0; nt < 2; ++nt) {
      #pragma unroll
      for (int r = 0; r < 4; ++r) {
        const int row = bm + wr + mt * 16 + quad * 4 + r;
        const int col = bn + wc + nt * 16 + l16;
        const size_t idx = (size_t)row * N + col;
        fout[idx] = acc[mt][nt][r] + bias[col] + resid[idx];
      }
    }
  }
}

// ---------------- LayerNorm: fp32 in -> bf16 out, one wave per token ----------
__global__ __launch_bounds__(256) void ln_kernel(
    const float* __restrict__ x, const float* __restrict__ w,
    const float* __restrict__ b, __bf16* __restrict__ out)
{
  const int wave = threadIdx.x >> 6, lane = threadIdx.x & 63;
  const int tok  = blockIdx.x * 4 + wave;
  const float* xr = x + (size_t)tok * C_;
  float4 v0 = ((const float4*)xr)[lane];
  float4 v1 = ((const float4*)xr)[lane + 64];
  float s = v0.x + v0.y + v0.z + v0.w + v1.x + v1.y + v1.z + v1.w;
  float q = v0.x*v0.x + v0.y*v0.y + v0.z*v0.z + v0.w*v0.w
          + v1.x*v1.x + v1.y*v1.y + v1.z*v1.z + v1.w*v1.w;
  #pragma unroll
  for (int off = 32; off >= 1; off >>= 1) {
    s += __shfl_xor(s, off, 64);
    q += __shfl_xor(q, off, 64);
  }
  const float mu  = s * (1.0f / C_);
  const float var = q * (1.0f / C_) - mu * mu;
  const float rs  = rsqrtf(var + 1e-5f);
  float4 w0 = ((const float4*)w)[lane], w1 = ((const float4*)w)[lane + 64];
  float4 b0 = ((const float4*)b)[lane], b1 = ((const float4*)b)[lane + 64];
  __bf16* orow = out + (size_t)tok * C_;
  const int c0 = lane * 4;
  orow[c0 + 0]       = (__bf16)((v0.x - mu) * rs * w0.x + b0.x);
  orow[c0 + 1]       = (__bf16)((v0.y - mu) * rs * w0.y + b0.y);
  orow[c0 + 2]       = (__bf16)((v0.z - mu) * rs * w0.z + b0.z);
  orow[c0 + 3]       = (__bf16)((v0.w - mu) * rs * w0.w + b0.w);
  orow[256 + c0 + 0] = (__bf16)((v1.x - mu) * rs * w1.x + b1.x);
  orow[256 + c0 + 1] = (__bf16)((v1.y - mu) * rs * w1.y + b1.y);
  orow[256 + c0 + 2] = (__bf16)((v1.z - mu) * rs * w1.z + b1.z);
  orow[256 + c0 + 3] = (__bf16)((v1.w - mu) * rs * w1.w + b1.w);
}

// ---------------- flash attention v7: 4 waves x 32 q, K/V reg-level reuse -----
// grid (16,32), block 256. Each K/V fragment read once per wave serves both
// 16-q column tiles (2 MFMAs) -> halved LDS traffic per q vs v6.
// Single-buffered K + V staged at iter top; 2 barriers/iter; cross-block
// overlap (3 blk/CU, LDS 41.5 KB) covers the DMA drain.
__global__ __launch_bounds__(256, 3) void flash_kernel(
    const __bf16* __restrict__ qb, const __bf16* __restrict__ kb,
    const __bf16* __restrict__ vtg, const float* __restrict__ rpb,
    __bf16* __restrict__ outb)
{
  __shared__ __align__(16) __bf16 kbuf[8192];       // [2 ks][128 key][32 d]
  __shared__ __align__(16) __bf16 vbuf[8192];       // [4 ks2][64 d][32 key], granule-swizzled
  __shared__ __align__(16) __bf16 biasC[2][2192];   // copy a: bias[i - a], *LOG2E
  const int tid  = threadIdx.x;
  const int wave = tid >> 6, lane = tid & 63;
  const int quad = lane >> 4, l16 = lane & 15;
  const int bh = blockIdx.y, h = bh & (H_ - 1);
  const int q0 = blockIdx.x * 128;
  const int boff = 1920 - q0;

  #pragma unroll
  for (int a = 0; a < 2; ++a)
    for (int i = tid; i < 2192; i += 256) {
      int ridx = i - a + boff;
      ridx = ridx < 0 ? 0 : (ridx > 2 * N_ - 2 ? 2 * N_ - 2 : ridx);
      biasC[a][i] = (__bf16)(rpb[(size_t)ridx * H_ + h] * LOG2E);
    }

  const __bf16* qptr = qb  + (size_t)bh * N_ * DH_;
  const __bf16* kptr = kb  + (size_t)bh * N_ * DH_;
  const __bf16* vtp  = vtg + (size_t)bh * N_ * DH_;

  // Q fragments (B-operand): q row = q0 + wave*32 + mt*16 + l16
  bf16x8 qf[2][2];
  #pragma unroll
  for (int mt = 0; mt < 2; ++mt)
    #pragma unroll
    for (int ks = 0; ks < 2; ++ks)
      qf[mt][ks] = *(const bf16x8*)(qptr +
          (size_t)(q0 + wave * 32 + mt * 16 + l16) * DH_ + ks * 32 + quad * 8);

  float l_i[2] = {0.f, 0.f};
  f32x4 o[2][4];
  const f32x4 fzero = {0.f, 0.f, 0.f, 0.f};
  #pragma unroll
  for (int mt = 0; mt < 2; ++mt)
    #pragma unroll
    for (int dt = 0; dt < 4; ++dt) o[mt][dt] = fzero;

  const int slr = lane >> 2;
  const int slc = lane & 3;
  const int vswz = (slr & 3) ^ ((slr >> 2) & 3);

  auto stageK = [&](int kcn) {
    #pragma unroll
    for (int j = 0; j < 4; ++j) {
      const int idx = wave * 4 + j;
      const int ks = idx & 1, g = idx >> 1;
      gld_lds16(kptr + (size_t)(kcn + g * 16 + slr) * DH_ + ks * 32 + slc * 8,
                &kbuf[ks * 4096 + g * 512]);
    }
  };
  auto stageV = [&](int kcn) {
    #pragma unroll
    for (int j = 0; j < 4; ++j) {
      const int idx = wave * 4 + j;
      const int ks2 = idx & 3, gg = idx >> 2;
      gld_lds16(vtp + (size_t)(gg * 16 + slr) * N_ + kcn + ks2 * 32 + (slc ^ vswz) * 8,
                &vbuf[ks2 * 2048 + gg * 512]);
    }
  };

  // bias base (mt=0): bb0 + kc + ct*16; mt=1 subtracts 16. Parity lane-fixed.
  const int bb0 = 127 + quad * 4 - wave * 32 - l16;
  const int acp = bb0 & 1;
  const __bf16* bcp = &biasC[acp][acp];

  for (int it = 0; it < 16; ++it) {
    const int kc = it << 7;
    __syncthreads();                 // prior iter reads (and bias fill) done
    stageK(kc);
    stageV(kc);
    __syncthreads();                 // K,V visible

    unsigned pk[2][8][2];
    float lp0 = 0.f, lp1 = 0.f;
    const __bf16* bp = bcp + kc + bb0;
    #pragma unroll
    for (int ct = 0; ct < 8; ++ct) {
      const bf16x8 kf0 = *(const bf16x8*)&kbuf[(ct * 16 + l16) * 32 + quad * 8];
      const bf16x8 kf1 = *(const bf16x8*)&kbuf[4096 + (ct * 16 + l16) * 32 + quad * 8];
      f32x4 s0 = __builtin_amdgcn_mfma_f32_16x16x32_bf16(kf0, qf[0][0], fzero, 0, 0, 0);
      s0 = __builtin_amdgcn_mfma_f32_16x16x32_bf16(kf1, qf[0][1], s0, 0, 0, 0);
      f32x4 s1 = __builtin_amdgcn_mfma_f32_16x16x32_bf16(kf0, qf[1][0], fzero, 0, 0, 0);
      s1 = __builtin_amdgcn_mfma_f32_16x16x32_bf16(kf1, qf[1][1], s1, 0, 0, 0);
      {
        const unsigned w0 = *(const unsigned*)(bp + ct * 16);
        const unsigned w1 = *(const unsigned*)(bp + ct * 16 + 2);
        const float p0 = __builtin_amdgcn_exp2f(s0[0] + __builtin_bit_cast(float, w0 << 16));
        const float p1 = __builtin_amdgcn_exp2f(s0[1] + __builtin_bit_cast(float, w0 & 0xFFFF0000u));
        const float p2 = __builtin_amdgcn_exp2f(s0[2] + __builtin_bit_cast(float, w1 << 16));
        const float p3 = __builtin_amdgcn_exp2f(s0[3] + __builtin_bit_cast(float, w1 & 0xFFFF0000u));
        lp0 += (p0 + p1) + (p2 + p3);
        pk[0][ct][0] = pack2_bf16(p0, p1);
        pk[0][ct][1] = pack2_bf16(p2, p3);
      }
      {
        const unsigned w0 = *(const unsigned*)(bp + ct * 16 - 16);
        const unsigned w1 = *(const unsigned*)(bp + ct * 16 - 14);
        const float p0 = __builtin_amdgcn_exp2f(s1[0] + __builtin_bit_cast(float, w0 << 16));
        const float p1 = __builtin_amdgcn_exp2f(s1[1] + __builtin_bit_cast(float, w0 & 0xFFFF0000u));
        const float p2 = __builtin_amdgcn_exp2f(s1[2] + __builtin_bit_cast(float, w1 << 16));
        const float p3 = __builtin_amdgcn_exp2f(s1[3] + __builtin_bit_cast(float, w1 & 0xFFFF0000u));
        lp1 += (p0 + p1) + (p2 + p3);
        pk[1][ct][0] = pack2_bf16(p0, p1);
        pk[1][ct][1] = pack2_bf16(p2, p3);
      }
    }
    l_i[0] += lp0;
    l_i[1] += lp1;

    // ---- PV: V-frag read once, used for both 16-q tiles
    #pragma unroll
    for (int ct = 0; ct < 8; ++ct) {
      const int gran = ((ct & 1) * 2 + (quad >> 1)) ^ ((l16 & 3) ^ ((l16 >> 2) & 3));
      const int vbase = (ct >> 1) * 2048 + l16 * 32 + gran * 8 + (quad & 1) * 4;
      const s16x4 pf0 = __builtin_bit_cast(s16x4, u32x2{pk[0][ct][0], pk[0][ct][1]});
      const s16x4 pf1 = __builtin_bit_cast(s16x4, u32x2{pk[1][ct][0], pk[1][ct][1]});
      #pragma unroll
      for (int dt = 0; dt < 4; ++dt) {
        const s16x4 vf = *(const s16x4*)&vbuf[vbase + dt * 512];
        o[0][dt] = __builtin_amdgcn_mfma_f32_16x16x16bf16_1k(vf, pf0, o[0][dt], 0, 0, 0);
        o[1][dt] = __builtin_amdgcn_mfma_f32_16x16x16bf16_1k(vf, pf1, o[1][dt], 0, 0, 0);
      }
    }
  }

  // ---- epilogue
  const int b = bh >> 3;
  #pragma unroll
  for (int mt = 0; mt < 2; ++mt) {
    float l = l_i[mt];
    l += __shfl_xor(l, 16, 64);
    l += __shfl_xor(l, 32, 64);
    const float inv = 1.0f / l;
    const int qg = q0 + wave * 32 + mt * 16 + l16;
    __bf16* orow = outb + ((size_t)(b * N_ + qg)) * C_ + h * DH_ + quad * 4;
    #pragma unroll
    for (int dt = 0; dt < 4; ++dt) {
      u32x2 pkd;
      pkd.x = pack2_bf16(o[mt][dt][0] * inv, o[mt][dt][1] * inv);
      pkd.y = pack2_bf16(o[mt][dt][2] * inv, o[mt][dt][3] * inv);
      *(u32x2*)(orow + dt * 16) = pkd;
    }
  }
}

// ---------------- merged fp32 -> bf16 weight cast (4 arrays, 1 launch) --------
__global__ void cast4_kernel(const float* __restrict__ s0, const float* __restrict__ s1,
                             const float* __restrict__ s2, const float* __restrict__ s3,
                             __bf16* __restrict__ d0, __bf16* __restrict__ d1,
                             __bf16* __restrict__ d2, __bf16* __restrict__ d3)
{
  const int i = (blockIdx.x * 256 + threadIdx.x) * 4;
  const float* s; __bf16* d; int off;
  if (i < 786432)       { s = s0; d = d0; off = i; }
  else if (i < 1048576) { s = s1; d = d1; off = i - 786432; }
  else if (i < 2097152) { s = s2; d = d2; off = i - 1048576; }
  else                  { s = s3; d = d3; off = i - 2097152; }
  const float4 v = *(const float4*)(s + off);
  u32x2 pk;
  pk.x = pack2_bf16(v.x, v.y);
  pk.y = pack2_bf16(v.z, v.w);
  *(u32x2*)(d + off) = pk;
}

extern "C" void kernel_launch(void* const* d_in, const int* in_sizes, int n_in,
                              void* d_out, int out_size, void* d_ws, size_t ws_size,
                              hipStream_t stream)
{
  const float* x      = (const float*)d_in[0];
  const float* qkv_w  = (const float*)d_in[1];
  const float* proj_w = (const float*)d_in[2];
  const float* proj_b = (const float*)d_in[3];
  const float* rpb    = (const float*)d_in[4];
  const float* n1w    = (const float*)d_in[5];
  const float* n1b    = (const float*)d_in[6];
  const float* n2w    = (const float*)d_in[7];
  const float* n2b    = (const float*)d_in[8];
  const float* fc1_w  = (const float*)d_in[9];
  const float* fc1_b  = (const float*)d_in[10];
  const float* fc2_w  = (const float*)d_in[11];
  const float* fc2_b  = (const float*)d_in[12];

  char* ws = (char*)d_ws;
  __bf16* hbuf = (__bf16*)(ws + 0);          // 8192*512  bf16
  __bf16* qbuf = (__bf16*)(ws + 8388608);    // [b,h,n,d] (pre-scaled by QSCALE)
  __bf16* kbuf = (__bf16*)(ws + 16777216);   // [b,h,n,d]
  __bf16* vbuf = (__bf16*)(ws + 25165824);   // V^T [b,h,d,n]
  __bf16* gelu = (__bf16*)(ws + 0);          // 8192*2048 bf16 (alias)
  __bf16* wq   = (__bf16*)(ws + 33554432);
  __bf16* wp   = (__bf16*)(ws + 35127296);
  __bf16* w1   = (__bf16*)(ws + 35651584);
  __bf16* w2   = (__bf16*)(ws + 37748736);
  __bf16* attn = (__bf16*)(ws + 39845888);   // 8192*512 bf16
  __bf16* h2in = attn;                       // alias
  float*  x1   = (float*)(ws + 48234496);    // 8192*512 fp32
  float*  outp = (float*)d_out;

  cast4_kernel<<<3072, 256, 0, stream>>>(qkv_w, proj_w, fc1_w, fc2_w, wq, wp, w1, w2);

  ln_kernel<<<2048, 256, 0, stream>>>(x, n1w, n1b, hbuf);

  gemm_bt<0><<<dim3(64, 12), 256, 0, stream>>>(hbuf, wq, MTOK, 1536, 512,
      nullptr, nullptr, qbuf, kbuf, vbuf);

  flash_kernel<<<dim3(16, 32), 256, 0, stream>>>(qbuf, kbuf, vbuf, rpb, attn);

  gemm_bt8<<<dim3(64, 8), 512, 0, stream>>>(attn, wp, MTOK, 512, 512,
      proj_b, x, x1);

  ln_kernel<<<2048, 256, 0, stream>>>(x1, n2w, n2b, h2in);

  gemm_bt<2><<<dim3(64, 16), 256, 0, stream>>>(h2in, w1, MTOK, 2048, 512,
      fc1_b, gelu, nullptr, nullptr, nullptr);

  gemm_bt8<<<dim3(64, 8), 512, 0, stream>>>(gelu, w2, MTOK, 512, 2048,
      fc2_b, x1, outp);
}

// Round 8
// 262.953 us; speedup vs baseline: 1.2123x; 1.0342x over previous
//
#include <hip/hip_runtime.h>
#include <hip/hip_bf16.h>
#include <math.h>

typedef __bf16 bf16x8 __attribute__((ext_vector_type(8)));
typedef float  f32x4  __attribute__((ext_vector_type(4)));
typedef short  s16x4  __attribute__((ext_vector_type(4)));
typedef unsigned int u32x2 __attribute__((ext_vector_type(2)));

#define B_   4
#define N_   2048
#define C_   512
#define H_   8
#define DH_  64
#define HID_ 2048
#define MTOK 8192
#define LOG2E 1.4426950408889634f
#define QSCALE 0.18033688011112042f   // 0.125 * log2(e), folded into Q store

__device__ inline void gld_lds16(const void* g, void* l) {
  __builtin_amdgcn_global_load_lds((const __attribute__((address_space(1))) void*)g,
                                   (__attribute__((address_space(3))) void*)l,
                                   16, 0, 0);
}

// round-half-up f32->bf16 pack via v_perm: 3 VALU per pair
__device__ inline unsigned pack2_bf16(float a, float b) {
  unsigned pa = __builtin_bit_cast(unsigned, a) + 0x8000u;
  unsigned pb = __builtin_bit_cast(unsigned, b) + 0x8000u;
  return __builtin_amdgcn_perm(pb, pa, 0x07060302u);  // lo16=pa.hi, hi16=pb.hi
}

// ---------------- C = A[M,K] * B[N,K]^T, 256-thr 128x128, dbuf K-loop ---------
// EPI 0: qkv split-store: q (x QSCALE), k -> [b,h,n,d]; v -> V^T [b,h,d,n]
// EPI 2: bout = gelu(acc + bias[col])    (bf16, tanh-form via exp2)
template<int EPI>
__global__ __launch_bounds__(256) void gemm_bt(
    const __bf16* __restrict__ A, const __bf16* __restrict__ Bw,
    int M, int N, int K,
    const float* __restrict__ bias, __bf16* __restrict__ bout,
    __bf16* __restrict__ qo, __bf16* __restrict__ ko, __bf16* __restrict__ vo)
{
  __shared__ __align__(16) __bf16 a_lds[2][128 * 32];
  __shared__ __align__(16) __bf16 b_lds[2][128 * 32];
  const int tid  = threadIdx.x;
  const int wave = tid >> 6, lane = tid & 63;
  const int quad = lane >> 4, l16 = lane & 15;
  const int bm = blockIdx.x * 128, bn = blockIdx.y * 128;
  const int wr = (wave >> 1) * 64, wc = (wave & 1) * 64;
  const int rw = lane >> 2;
  const int c4 = lane & 3;

  const f32x4 fzero = {0.f, 0.f, 0.f, 0.f};
  f32x4 acc[4][4];
  #pragma unroll
  for (int i = 0; i < 4; ++i)
    #pragma unroll
    for (int j = 0; j < 4; ++j) acc[i][j] = fzero;

  auto stage = [&](int buf, int k0) {
    #pragma unroll
    for (int j = 0; j < 2; ++j) {
      const int rbase = wave * 32 + j * 16;
      gld_lds16(A + (size_t)(bm + rbase + rw) * K + k0 + c4 * 8, &a_lds[buf][rbase * 32]);
      gld_lds16(Bw + (size_t)(bn + rbase + rw) * K + k0 + c4 * 8, &b_lds[buf][rbase * 32]);
    }
  };

  const int nk = K >> 5;
  stage(0, 0);
  for (int ki = 0; ki < nk; ++ki) {
    const int cur = ki & 1;
    __syncthreads();
    if (ki + 1 < nk) stage(cur ^ 1, (ki + 1) << 5);
    bf16x8 af[4], bf[4];
    #pragma unroll
    for (int t = 0; t < 4; ++t)
      af[t] = *(const bf16x8*)&a_lds[cur][(wr + t * 16 + l16) * 32 + quad * 8];
    #pragma unroll
    for (int t = 0; t < 4; ++t)
      bf[t] = *(const bf16x8*)&b_lds[cur][(wc + t * 16 + l16) * 32 + quad * 8];
    #pragma unroll
    for (int mt = 0; mt < 4; ++mt)
      #pragma unroll
      for (int nt = 0; nt < 4; ++nt)
        acc[mt][nt] = __builtin_amdgcn_mfma_f32_16x16x32_bf16(af[mt], bf[nt], acc[mt][nt], 0, 0, 0);
  }

  #pragma unroll
  for (int mt = 0; mt < 4; ++mt) {
    #pragma unroll
    for (int nt = 0; nt < 4; ++nt) {
      #pragma unroll
      for (int r = 0; r < 4; ++r) {
        const int row = bm + wr + mt * 16 + quad * 4 + r;
        const int col = bn + wc + nt * 16 + l16;
        float v = acc[mt][nt][r];
        if (EPI == 0) {
          const int b = row >> 11, n = row & (N_ - 1);
          const int s = col >> 9, h = (col >> 6) & (H_ - 1), d = col & (DH_ - 1);
          if (s == 2) {
            vo[((((size_t)b * H_ + h) * DH_ + d) << 11) + n] = (__bf16)v;
          } else if (s == 1) {
            ko[((((size_t)b * H_ + h) * N_ + n) << 6) + d] = (__bf16)v;
          } else {
            qo[((((size_t)b * H_ + h) * N_ + n) << 6) + d] = (__bf16)(v * QSCALE);
          }
        } else {
          // gelu, tanh form: g = x * t / (t + 1), t = exp2(2*c*log2e*(x + 0.044715x^3))
          const float xg = v + bias[col];
          const float x2 = xg * xg;
          const float u  = __builtin_fmaf(0.044715f * x2, xg, xg);
          const float t  = __builtin_amdgcn_exp2f(u * 2.3022082f);
          const float g  = xg * t * __builtin_amdgcn_rcpf(t + 1.0f);
          bout[(size_t)row * N + col] = (__bf16)g;
        }
      }
    }
  }
}

// ---------------- C = A[M,K] * B[N,K]^T, 512-thr 128x64, fused resid (fp32) ---
__global__ __launch_bounds__(512) void gemm_bt8(
    const __bf16* __restrict__ A, const __bf16* __restrict__ Bw,
    int M, int N, int K,
    const float* __restrict__ bias, const float* __restrict__ resid,
    float* __restrict__ fout)
{
  __shared__ __align__(16) __bf16 a_lds[2][128 * 32];
  __shared__ __align__(16) __bf16 b_lds[2][64 * 32];
  const int tid  = threadIdx.x;
  const int wave = tid >> 6, lane = tid & 63;
  const int quad = lane >> 4, l16 = lane & 15;
  const int bm = blockIdx.x * 128, bn = blockIdx.y * 64;
  const int wr = (wave >> 1) * 32, wc = (wave & 1) * 32;
  const int rw = lane >> 2;
  const int c4 = lane & 3;

  const f32x4 fzero = {0.f, 0.f, 0.f, 0.f};
  f32x4 acc[2][2];
  #pragma unroll
  for (int i = 0; i < 2; ++i)
    #pragma unroll
    for (int j = 0; j < 2; ++j) acc[i][j] = fzero;

  auto stage = [&](int buf, int k0) {
    gld_lds16(A + (size_t)(bm + wave * 16 + rw) * K + k0 + c4 * 8, &a_lds[buf][wave * 512]);
    if (wave < 4)
      gld_lds16(Bw + (size_t)(bn + wave * 16 + rw) * K + k0 + c4 * 8, &b_lds[buf][wave * 512]);
  };

  const int nk = K >> 5;
  stage(0, 0);
  for (int ki = 0; ki < nk; ++ki) {
    const int cur = ki & 1;
    __syncthreads();
    if (ki + 1 < nk) stage(cur ^ 1, (ki + 1) << 5);
    bf16x8 af[2], bf[2];
    #pragma unroll
    for (int t = 0; t < 2; ++t)
      af[t] = *(const bf16x8*)&a_lds[cur][(wr + t * 16 + l16) * 32 + quad * 8];
    #pragma unroll
    for (int t = 0; t < 2; ++t)
      bf[t] = *(const bf16x8*)&b_lds[cur][(wc + t * 16 + l16) * 32 + quad * 8];
    #pragma unroll
    for (int mt = 0; mt < 2; ++mt)
      #pragma unroll
      for (int nt = 0; nt < 2; ++nt)
        acc[mt][nt] = __builtin_amdgcn_mfma_f32_16x16x32_bf16(af[mt], bf[nt], acc[mt][nt], 0, 0, 0);
  }

  #pragma unroll
  for (int mt = 0; mt < 2; ++mt) {
    #pragma unroll
    for (int nt = 0; nt < 2; ++nt) {
      #pragma unroll
      for (int r = 0; r < 4; ++r) {
        const int row = bm + wr + mt * 16 + quad * 4 + r;
        const int col = bn + wc + nt * 16 + l16;
        const size_t idx = (size_t)row * N + col;
        fout[idx] = acc[mt][nt][r] + bias[col] + resid[idx];
      }
    }
  }
}

// ---------------- LayerNorm: fp32 in -> bf16 out, one wave per token ----------
__global__ __launch_bounds__(256) void ln_kernel(
    const float* __restrict__ x, const float* __restrict__ w,
    const float* __restrict__ b, __bf16* __restrict__ out)
{
  const int wave = threadIdx.x >> 6, lane = threadIdx.x & 63;
  const int tok  = blockIdx.x * 4 + wave;
  const float* xr = x + (size_t)tok * C_;
  float4 v0 = ((const float4*)xr)[lane];
  float4 v1 = ((const float4*)xr)[lane + 64];
  float s = v0.x + v0.y + v0.z + v0.w + v1.x + v1.y + v1.z + v1.w;
  float q = v0.x*v0.x + v0.y*v0.y + v0.z*v0.z + v0.w*v0.w
          + v1.x*v1.x + v1.y*v1.y + v1.z*v1.z + v1.w*v1.w;
  #pragma unroll
  for (int off = 32; off >= 1; off >>= 1) {
    s += __shfl_xor(s, off, 64);
    q += __shfl_xor(q, off, 64);
  }
  const float mu  = s * (1.0f / C_);
  const float var = q * (1.0f / C_) - mu * mu;
  const float rs  = rsqrtf(var + 1e-5f);
  float4 w0 = ((const float4*)w)[lane], w1 = ((const float4*)w)[lane + 64];
  float4 b0 = ((const float4*)b)[lane], b1 = ((const float4*)b)[lane + 64];
  __bf16* orow = out + (size_t)tok * C_;
  const int c0 = lane * 4;
  orow[c0 + 0]       = (__bf16)((v0.x - mu) * rs * w0.x + b0.x);
  orow[c0 + 1]       = (__bf16)((v0.y - mu) * rs * w0.y + b0.y);
  orow[c0 + 2]       = (__bf16)((v0.z - mu) * rs * w0.z + b0.z);
  orow[c0 + 3]       = (__bf16)((v0.w - mu) * rs * w0.w + b0.w);
  orow[256 + c0 + 0] = (__bf16)((v1.x - mu) * rs * w1.x + b1.x);
  orow[256 + c0 + 1] = (__bf16)((v1.y - mu) * rs * w1.y + b1.y);
  orow[256 + c0 + 2] = (__bf16)((v1.z - mu) * rs * w1.z + b1.z);
  orow[256 + c0 + 3] = (__bf16)((v1.w - mu) * rs * w1.w + b1.w);
}

// ---------------- flash attention v8: VALU-diet v7 ----------------------------
// v7 structure (4 waves x 32 q, 2 barriers/iter, reg-level K/V reuse) plus:
//  - bias folded into QK MFMA C-operand (no per-element adds)
//  - l computed by all-ones-A MFMA (no VALU sums, no epilogue shuffles)
//  - v_perm bf16 pack
__global__ __launch_bounds__(256, 3) void flash_kernel(
    const __bf16* __restrict__ qb, const __bf16* __restrict__ kb,
    const __bf16* __restrict__ vtg, const float* __restrict__ rpb,
    __bf16* __restrict__ outb)
{
  __shared__ __align__(16) __bf16 kbuf[8192];       // [2 ks][128 key][32 d]
  __shared__ __align__(16) __bf16 vbuf[8192];       // [4 ks2][64 d][32 key], granule-swizzled
  __shared__ __align__(16) __bf16 biasC[2][2192];   // copy a: bias[i - a], *LOG2E
  const int tid  = threadIdx.x;
  const int wave = tid >> 6, lane = tid & 63;
  const int quad = lane >> 4, l16 = lane & 15;
  const int bh = blockIdx.y, h = bh & (H_ - 1);
  const int q0 = blockIdx.x * 128;
  const int boff = 1920 - q0;

  #pragma unroll
  for (int a = 0; a < 2; ++a)
    for (int i = tid; i < 2192; i += 256) {
      int ridx = i - a + boff;
      ridx = ridx < 0 ? 0 : (ridx > 2 * N_ - 2 ? 2 * N_ - 2 : ridx);
      biasC[a][i] = (__bf16)(rpb[(size_t)ridx * H_ + h] * LOG2E);
    }

  const __bf16* qptr = qb  + (size_t)bh * N_ * DH_;
  const __bf16* kptr = kb  + (size_t)bh * N_ * DH_;
  const __bf16* vtp  = vtg + (size_t)bh * N_ * DH_;

  bf16x8 qf[2][2];
  #pragma unroll
  for (int mt = 0; mt < 2; ++mt)
    #pragma unroll
    for (int ks = 0; ks < 2; ++ks)
      qf[mt][ks] = *(const bf16x8*)(qptr +
          (size_t)(q0 + wave * 32 + mt * 16 + l16) * DH_ + ks * 32 + quad * 8);

  const f32x4 fzero = {0.f, 0.f, 0.f, 0.f};
  f32x4 o[2][4];
  f32x4 la[2] = {fzero, fzero};     // l accumulators (ones-MFMA)
  #pragma unroll
  for (int mt = 0; mt < 2; ++mt)
    #pragma unroll
    for (int dt = 0; dt < 4; ++dt) o[mt][dt] = fzero;

  const short one_bf16 = (short)0x3F80;
  const s16x4 ones = {one_bf16, one_bf16, one_bf16, one_bf16};

  const int slr = lane >> 2;
  const int slc = lane & 3;
  const int vswz = (slr & 3) ^ ((slr >> 2) & 3);

  auto stageK = [&](int kcn) {
    #pragma unroll
    for (int j = 0; j < 4; ++j) {
      const int idx = wave * 4 + j;
      const int ks = idx & 1, g = idx >> 1;
      gld_lds16(kptr + (size_t)(kcn + g * 16 + slr) * DH_ + ks * 32 + slc * 8,
                &kbuf[ks * 4096 + g * 512]);
    }
  };
  auto stageV = [&](int kcn) {
    #pragma unroll
    for (int j = 0; j < 4; ++j) {
      const int idx = wave * 4 + j;
      const int ks2 = idx & 3, gg = idx >> 2;
      gld_lds16(vtp + (size_t)(gg * 16 + slr) * N_ + kcn + ks2 * 32 + (slc ^ vswz) * 8,
                &vbuf[ks2 * 2048 + gg * 512]);
    }
  };

  const int bb0 = 127 + quad * 4 - wave * 32 - l16;
  const int acp = bb0 & 1;
  const __bf16* bcp = &biasC[acp][acp];

  for (int it = 0; it < 16; ++it) {
    const int kc = it << 7;
    __syncthreads();                 // prior iter reads (and bias fill) done
    stageK(kc);
    stageV(kc);
    __syncthreads();                 // K,V visible

    unsigned pk[2][8][2];
    const __bf16* bp = bcp + kc + bb0;
    #pragma unroll
    for (int ct = 0; ct < 8; ++ct) {
      const bf16x8 kf0 = *(const bf16x8*)&kbuf[(ct * 16 + l16) * 32 + quad * 8];
      const bf16x8 kf1 = *(const bf16x8*)&kbuf[4096 + (ct * 16 + l16) * 32 + quad * 8];
      // bias as C-operand (f32 unpack of 2 aligned b32 reads per tile)
      const unsigned w0 = *(const unsigned*)(bp + ct * 16);
      const unsigned w1 = *(const unsigned*)(bp + ct * 16 + 2);
      const unsigned x0 = *(const unsigned*)(bp + ct * 16 - 16);
      const unsigned x1 = *(const unsigned*)(bp + ct * 16 - 14);
      const f32x4 c0 = {__builtin_bit_cast(float, w0 << 16),
                        __builtin_bit_cast(float, w0 & 0xFFFF0000u),
                        __builtin_bit_cast(float, w1 << 16),
                        __builtin_bit_cast(float, w1 & 0xFFFF0000u)};
      const f32x4 c1 = {__builtin_bit_cast(float, x0 << 16),
                        __builtin_bit_cast(float, x0 & 0xFFFF0000u),
                        __builtin_bit_cast(float, x1 << 16),
                        __builtin_bit_cast(float, x1 & 0xFFFF0000u)};
      f32x4 s0 = __builtin_amdgcn_mfma_f32_16x16x32_bf16(kf0, qf[0][0], c0, 0, 0, 0);
      s0 = __builtin_amdgcn_mfma_f32_16x16x32_bf16(kf1, qf[0][1], s0, 0, 0, 0);
      f32x4 s1 = __builtin_amdgcn_mfma_f32_16x16x32_bf16(kf0, qf[1][0], c1, 0, 0, 0);
      s1 = __builtin_amdgcn_mfma_f32_16x16x32_bf16(kf1, qf[1][1], s1, 0, 0, 0);
      {
        const float p0 = __builtin_amdgcn_exp2f(s0[0]);
        const float p1 = __builtin_amdgcn_exp2f(s0[1]);
        const float p2 = __builtin_amdgcn_exp2f(s0[2]);
        const float p3 = __builtin_amdgcn_exp2f(s0[3]);
        pk[0][ct][0] = pack2_bf16(p0, p1);
        pk[0][ct][1] = pack2_bf16(p2, p3);
      }
      {
        const float p0 = __builtin_amdgcn_exp2f(s1[0]);
        const float p1 = __builtin_amdgcn_exp2f(s1[1]);
        const float p2 = __builtin_amdgcn_exp2f(s1[2]);
        const float p3 = __builtin_amdgcn_exp2f(s1[3]);
        pk[1][ct][0] = pack2_bf16(p0, p1);
        pk[1][ct][1] = pack2_bf16(p2, p3);
      }
    }

    // ---- PV + l: V-frag read once, used for both 16-q tiles
    #pragma unroll
    for (int ct = 0; ct < 8; ++ct) {
      const int gran = ((ct & 1) * 2 + (quad >> 1)) ^ ((l16 & 3) ^ ((l16 >> 2) & 3));
      const int vbase = (ct >> 1) * 2048 + l16 * 32 + gran * 8 + (quad & 1) * 4;
      const s16x4 pf0 = __builtin_bit_cast(s16x4, u32x2{pk[0][ct][0], pk[0][ct][1]});
      const s16x4 pf1 = __builtin_bit_cast(s16x4, u32x2{pk[1][ct][0], pk[1][ct][1]});
      la[0] = __builtin_amdgcn_mfma_f32_16x16x16bf16_1k(ones, pf0, la[0], 0, 0, 0);
      la[1] = __builtin_amdgcn_mfma_f32_16x16x16bf16_1k(ones, pf1, la[1], 0, 0, 0);
      #pragma unroll
      for (int dt = 0; dt < 4; ++dt) {
        const s16x4 vf = *(const s16x4*)&vbuf[vbase + dt * 512];
        o[0][dt] = __builtin_amdgcn_mfma_f32_16x16x16bf16_1k(vf, pf0, o[0][dt], 0, 0, 0);
        o[1][dt] = __builtin_amdgcn_mfma_f32_16x16x16bf16_1k(vf, pf1, o[1][dt], 0, 0, 0);
      }
    }
  }

  // ---- epilogue: la already holds full l per q-column (no shuffles)
  const int b = bh >> 3;
  #pragma unroll
  for (int mt = 0; mt < 2; ++mt) {
    const float inv = 1.0f / la[mt][0];
    const int qg = q0 + wave * 32 + mt * 16 + l16;
    __bf16* orow = outb + ((size_t)(b * N_ + qg)) * C_ + h * DH_ + quad * 4;
    #pragma unroll
    for (int dt = 0; dt < 4; ++dt) {
      u32x2 pkd;
      pkd.x = pack2_bf16(o[mt][dt][0] * inv, o[mt][dt][1] * inv);
      pkd.y = pack2_bf16(o[mt][dt][2] * inv, o[mt][dt][3] * inv);
      *(u32x2*)(orow + dt * 16) = pkd;
    }
  }
}

// ---------------- merged fp32 -> bf16 weight cast (4 arrays, 1 launch) --------
__global__ void cast4_kernel(const float* __restrict__ s0, const float* __restrict__ s1,
                             const float* __restrict__ s2, const float* __restrict__ s3,
                             __bf16* __restrict__ d0, __bf16* __restrict__ d1,
                             __bf16* __restrict__ d2, __bf16* __restrict__ d3)
{
  const int i = (blockIdx.x * 256 + threadIdx.x) * 4;
  const float* s; __bf16* d; int off;
  if (i < 786432)       { s = s0; d = d0; off = i; }
  else if (i < 1048576) { s = s1; d = d1; off = i - 786432; }
  else if (i < 2097152) { s = s2; d = d2; off = i - 1048576; }
  else                  { s = s3; d = d3; off = i - 2097152; }
  const float4 v = *(const float4*)(s + off);
  u32x2 pk;
  pk.x = pack2_bf16(v.x, v.y);
  pk.y = pack2_bf16(v.z, v.w);
  *(u32x2*)(d + off) = pk;
}

extern "C" void kernel_launch(void* const* d_in, const int* in_sizes, int n_in,
                              void* d_out, int out_size, void* d_ws, size_t ws_size,
                              hipStream_t stream)
{
  const float* x      = (const float*)d_in[0];
  const float* qkv_w  = (const float*)d_in[1];
  const float* proj_w = (const float*)d_in[2];
  const float* proj_b = (const float*)d_in[3];
  const float* rpb    = (const float*)d_in[4];
  const float* n1w    = (const float*)d_in[5];
  const float* n1b    = (const float*)d_in[6];
  const float* n2w    = (const float*)d_in[7];
  const float* n2b    = (const float*)d_in[8];
  const float* fc1_w  = (const float*)d_in[9];
  const float* fc1_b  = (const float*)d_in[10];
  const float* fc2_w  = (const float*)d_in[11];
  const float* fc2_b  = (const float*)d_in[12];

  char* ws = (char*)d_ws;
  __bf16* hbuf = (__bf16*)(ws + 0);          // 8192*512  bf16
  __bf16* qbuf = (__bf16*)(ws + 8388608);    // [b,h,n,d] (pre-scaled by QSCALE)
  __bf16* kbuf = (__bf16*)(ws + 16777216);   // [b,h,n,d]
  __bf16* vbuf = (__bf16*)(ws + 25165824);   // V^T [b,h,d,n]
  __bf16* gelu = (__bf16*)(ws + 0);          // 8192*2048 bf16 (alias)
  __bf16* wq   = (__bf16*)(ws + 33554432);
  __bf16* wp   = (__bf16*)(ws + 35127296);
  __bf16* w1   = (__bf16*)(ws + 35651584);
  __bf16* w2   = (__bf16*)(ws + 37748736);
  __bf16* attn = (__bf16*)(ws + 39845888);   // 8192*512 bf16
  __bf16* h2in = attn;                       // alias
  float*  x1   = (float*)(ws + 48234496);    // 8192*512 fp32
  float*  outp = (float*)d_out;

  cast4_kernel<<<3072, 256, 0, stream>>>(qkv_w, proj_w, fc1_w, fc2_w, wq, wp, w1, w2);

  ln_kernel<<<2048, 256, 0, stream>>>(x, n1w, n1b, hbuf);

  gemm_bt<0><<<dim3(64, 12), 256, 0, stream>>>(hbuf, wq, MTOK, 1536, 512,
      nullptr, nullptr, qbuf, kbuf, vbuf);

  flash_kernel<<<dim3(16, 32), 256, 0, stream>>>(qbuf, kbuf, vbuf, rpb, attn);

  gemm_bt8<<<dim3(64, 8), 512, 0, stream>>>(attn, wp, MTOK, 512, 512,
      proj_b, x, x1);

  ln_kernel<<<2048, 256, 0, stream>>>(x1, n2w, n2b, h2in);

  gemm_bt<2><<<dim3(64, 16), 256, 0, stream>>>(h2in, w1, MTOK, 2048, 512,
      fc1_b, gelu, nullptr, nullptr, nullptr);

  gemm_bt8<<<dim3(64, 8), 512, 0, stream>>>(gelu, w2, MTOK, 512, 2048,
      fc2_b, x1, outp);
}

// Round 9
// 261.816 us; speedup vs baseline: 1.2176x; 1.0043x over previous
//
#include <hip/hip_runtime.h>
#include <hip/hip_bf16.h>
#include <math.h>

typedef __bf16 bf16x8 __attribute__((ext_vector_type(8)));
typedef float  f32x4  __attribute__((ext_vector_type(4)));
typedef short  s16x4  __attribute__((ext_vector_type(4)));
typedef unsigned int u32x2 __attribute__((ext_vector_type(2)));

#define B_   4
#define N_   2048
#define C_   512
#define H_   8
#define DH_  64
#define HID_ 2048
#define MTOK 8192
#define LOG2E 1.4426950408889634f
#define QSCALE 0.18033688011112042f   // 0.125 * log2(e), folded into Q store

__device__ inline void gld_lds16(const void* g, void* l) {
  __builtin_amdgcn_global_load_lds((const __attribute__((address_space(1))) void*)g,
                                   (__attribute__((address_space(3))) void*)l,
                                   16, 0, 0);
}

// round-half-up f32->bf16 pack via v_perm: 3 VALU per pair
__device__ inline unsigned pack2_bf16(float a, float b) {
  unsigned pa = __builtin_bit_cast(unsigned, a) + 0x8000u;
  unsigned pb = __builtin_bit_cast(unsigned, b) + 0x8000u;
  return __builtin_amdgcn_perm(pb, pa, 0x07060302u);  // lo16=pa.hi, hi16=pb.hi
}

// ---------------- C = A[M,K] * B[N,K]^T, 512-thr, 1-barrier dbuf K-loop -------
// 8 waves; BN=128: wave tile 32x64 (acc 2x4); BN=64: 32x32 (acc 2x2).
// EPI 0: qkv split-store: q (x QSCALE), k -> [b,h,n,d]; v -> V^T [b,h,d,n]
// EPI 1: fout = acc + bias[col] + resid  (fp32)
// EPI 2: bout = gelu(acc + bias[col])    (bf16, tanh-form via exp2)
template<int EPI, int BN>
__global__ __launch_bounds__(512, 4) void gemm512(
    const __bf16* __restrict__ A, const __bf16* __restrict__ Bw,
    int M, int N, int K,
    const float* __restrict__ bias, const float* __restrict__ resid,
    float* __restrict__ fout, __bf16* __restrict__ bout,
    __bf16* __restrict__ qo, __bf16* __restrict__ ko, __bf16* __restrict__ vo)
{
  constexpr int NT = (BN == 128) ? 4 : 2;
  __shared__ __align__(16) __bf16 a_lds[2][128 * 32];
  __shared__ __align__(16) __bf16 b_lds[2][BN * 32];
  const int tid  = threadIdx.x;
  const int wave = tid >> 6, lane = tid & 63;
  const int quad = lane >> 4, l16 = lane & 15;
  const int bm = blockIdx.x * 128, bn = blockIdx.y * BN;
  const int wr = (wave >> 1) * 32;
  const int wc = (wave & 1) * (BN == 128 ? 64 : 32);
  const int srow = tid >> 2;        // 0..127 staging row
  const int c4   = lane & 3;        // 16B chunk

  const f32x4 fzero = {0.f, 0.f, 0.f, 0.f};
  f32x4 acc[2][NT];
  #pragma unroll
  for (int i = 0; i < 2; ++i)
    #pragma unroll
    for (int j = 0; j < NT; ++j) acc[i][j] = fzero;

  auto stage = [&](int buf, int k0) {
    gld_lds16(A + (size_t)(bm + srow) * K + k0 + c4 * 8, &a_lds[buf][wave * 512]);
    if (BN == 128 || wave < 4)
      gld_lds16(Bw + (size_t)(bn + srow) * K + k0 + c4 * 8, &b_lds[buf][wave * 512]);
  };

  const int nk = K >> 5;
  stage(0, 0);
  for (int ki = 0; ki < nk; ++ki) {
    const int cur = ki & 1;
    __syncthreads();
    if (ki + 1 < nk) stage(cur ^ 1, (ki + 1) << 5);
    bf16x8 af[2], bf[NT];
    #pragma unroll
    for (int t = 0; t < 2; ++t)
      af[t] = *(const bf16x8*)&a_lds[cur][(wr + t * 16 + l16) * 32 + quad * 8];
    #pragma unroll
    for (int t = 0; t < NT; ++t)
      bf[t] = *(const bf16x8*)&b_lds[cur][(wc + t * 16 + l16) * 32 + quad * 8];
    #pragma unroll
    for (int mt = 0; mt < 2; ++mt)
      #pragma unroll
      for (int nt = 0; nt < NT; ++nt)
        acc[mt][nt] = __builtin_amdgcn_mfma_f32_16x16x32_bf16(af[mt], bf[nt], acc[mt][nt], 0, 0, 0);
  }

  #pragma unroll
  for (int mt = 0; mt < 2; ++mt) {
    #pragma unroll
    for (int nt = 0; nt < NT; ++nt) {
      #pragma unroll
      for (int r = 0; r < 4; ++r) {
        const int row = bm + wr + mt * 16 + quad * 4 + r;
        const int col = bn + wc + nt * 16 + l16;
        float v = acc[mt][nt][r];
        if (EPI == 0) {
          const int b = row >> 11, n = row & (N_ - 1);
          const int s = col >> 9, h = (col >> 6) & (H_ - 1), d = col & (DH_ - 1);
          if (s == 2) {
            vo[((((size_t)b * H_ + h) * DH_ + d) << 11) + n] = (__bf16)v;
          } else if (s == 1) {
            ko[((((size_t)b * H_ + h) * N_ + n) << 6) + d] = (__bf16)v;
          } else {
            qo[((((size_t)b * H_ + h) * N_ + n) << 6) + d] = (__bf16)(v * QSCALE);
          }
        } else if (EPI == 1) {
          const size_t idx = (size_t)row * N + col;
          fout[idx] = v + bias[col] + resid[idx];
        } else {
          // gelu, tanh form: g = x * t / (t + 1), t = exp2(2*c*log2e*(x + 0.044715x^3))
          const float xg = v + bias[col];
          const float x2 = xg * xg;
          const float u  = __builtin_fmaf(0.044715f * x2, xg, xg);
          const float t  = __builtin_amdgcn_exp2f(u * 2.3022082f);
          const float g  = xg * t * __builtin_amdgcn_rcpf(t + 1.0f);
          bout[(size_t)row * N + col] = (__bf16)g;
        }
      }
    }
  }
}

// ---------------- LayerNorm: fp32 in -> bf16 out, one wave per token ----------
__global__ __launch_bounds__(256) void ln_kernel(
    const float* __restrict__ x, const float* __restrict__ w,
    const float* __restrict__ b, __bf16* __restrict__ out)
{
  const int wave = threadIdx.x >> 6, lane = threadIdx.x & 63;
  const int tok  = blockIdx.x * 4 + wave;
  const float* xr = x + (size_t)tok * C_;
  float4 v0 = ((const float4*)xr)[lane];
  float4 v1 = ((const float4*)xr)[lane + 64];
  float s = v0.x + v0.y + v0.z + v0.w + v1.x + v1.y + v1.z + v1.w;
  float q = v0.x*v0.x + v0.y*v0.y + v0.z*v0.z + v0.w*v0.w
          + v1.x*v1.x + v1.y*v1.y + v1.z*v1.z + v1.w*v1.w;
  #pragma unroll
  for (int off = 32; off >= 1; off >>= 1) {
    s += __shfl_xor(s, off, 64);
    q += __shfl_xor(q, off, 64);
  }
  const float mu  = s * (1.0f / C_);
  const float var = q * (1.0f / C_) - mu * mu;
  const float rs  = rsqrtf(var + 1e-5f);
  float4 w0 = ((const float4*)w)[lane], w1 = ((const float4*)w)[lane + 64];
  float4 b0 = ((const float4*)b)[lane], b1 = ((const float4*)b)[lane + 64];
  __bf16* orow = out + (size_t)tok * C_;
  const int c0 = lane * 4;
  orow[c0 + 0]       = (__bf16)((v0.x - mu) * rs * w0.x + b0.x);
  orow[c0 + 1]       = (__bf16)((v0.y - mu) * rs * w0.y + b0.y);
  orow[c0 + 2]       = (__bf16)((v0.z - mu) * rs * w0.z + b0.z);
  orow[c0 + 3]       = (__bf16)((v0.w - mu) * rs * w0.w + b0.w);
  orow[256 + c0 + 0] = (__bf16)((v1.x - mu) * rs * w1.x + b1.x);
  orow[256 + c0 + 1] = (__bf16)((v1.y - mu) * rs * w1.y + b1.y);
  orow[256 + c0 + 2] = (__bf16)((v1.z - mu) * rs * w1.z + b1.z);
  orow[256 + c0 + 3] = (__bf16)((v1.w - mu) * rs * w1.w + b1.w);
}

// ---------------- flash attention v8: VALU-diet (unchanged from R8) -----------
__global__ __launch_bounds__(256, 3) void flash_kernel(
    const __bf16* __restrict__ qb, const __bf16* __restrict__ kb,
    const __bf16* __restrict__ vtg, const float* __restrict__ rpb,
    __bf16* __restrict__ outb)
{
  __shared__ __align__(16) __bf16 kbuf[8192];       // [2 ks][128 key][32 d]
  __shared__ __align__(16) __bf16 vbuf[8192];       // [4 ks2][64 d][32 key], granule-swizzled
  __shared__ __align__(16) __bf16 biasC[2][2192];   // copy a: bias[i - a], *LOG2E
  const int tid  = threadIdx.x;
  const int wave = tid >> 6, lane = tid & 63;
  const int quad = lane >> 4, l16 = lane & 15;
  const int bh = blockIdx.y, h = bh & (H_ - 1);
  const int q0 = blockIdx.x * 128;
  const int boff = 1920 - q0;

  #pragma unroll
  for (int a = 0; a < 2; ++a)
    for (int i = tid; i < 2192; i += 256) {
      int ridx = i - a + boff;
      ridx = ridx < 0 ? 0 : (ridx > 2 * N_ - 2 ? 2 * N_ - 2 : ridx);
      biasC[a][i] = (__bf16)(rpb[(size_t)ridx * H_ + h] * LOG2E);
    }

  const __bf16* qptr = qb  + (size_t)bh * N_ * DH_;
  const __bf16* kptr = kb  + (size_t)bh * N_ * DH_;
  const __bf16* vtp  = vtg + (size_t)bh * N_ * DH_;

  bf16x8 qf[2][2];
  #pragma unroll
  for (int mt = 0; mt < 2; ++mt)
    #pragma unroll
    for (int ks = 0; ks < 2; ++ks)
      qf[mt][ks] = *(const bf16x8*)(qptr +
          (size_t)(q0 + wave * 32 + mt * 16 + l16) * DH_ + ks * 32 + quad * 8);

  const f32x4 fzero = {0.f, 0.f, 0.f, 0.f};
  f32x4 o[2][4];
  f32x4 la[2] = {fzero, fzero};     // l accumulators (ones-MFMA)
  #pragma unroll
  for (int mt = 0; mt < 2; ++mt)
    #pragma unroll
    for (int dt = 0; dt < 4; ++dt) o[mt][dt] = fzero;

  const short one_bf16 = (short)0x3F80;
  const s16x4 ones = {one_bf16, one_bf16, one_bf16, one_bf16};

  const int slr = lane >> 2;
  const int slc = lane & 3;
  const int vswz = (slr & 3) ^ ((slr >> 2) & 3);

  auto stageK = [&](int kcn) {
    #pragma unroll
    for (int j = 0; j < 4; ++j) {
      const int idx = wave * 4 + j;
      const int ks = idx & 1, g = idx >> 1;
      gld_lds16(kptr + (size_t)(kcn + g * 16 + slr) * DH_ + ks * 32 + slc * 8,
                &kbuf[ks * 4096 + g * 512]);
    }
  };
  auto stageV = [&](int kcn) {
    #pragma unroll
    for (int j = 0; j < 4; ++j) {
      const int idx = wave * 4 + j;
      const int ks2 = idx & 3, gg = idx >> 2;
      gld_lds16(vtp + (size_t)(gg * 16 + slr) * N_ + kcn + ks2 * 32 + (slc ^ vswz) * 8,
                &vbuf[ks2 * 2048 + gg * 512]);
    }
  };

  const int bb0 = 127 + quad * 4 - wave * 32 - l16;
  const int acp = bb0 & 1;
  const __bf16* bcp = &biasC[acp][acp];

  for (int it = 0; it < 16; ++it) {
    const int kc = it << 7;
    __syncthreads();                 // prior iter reads (and bias fill) done
    stageK(kc);
    stageV(kc);
    __syncthreads();                 // K,V visible

    unsigned pk[2][8][2];
    const __bf16* bp = bcp + kc + bb0;
    #pragma unroll
    for (int ct = 0; ct < 8; ++ct) {
      const bf16x8 kf0 = *(const bf16x8*)&kbuf[(ct * 16 + l16) * 32 + quad * 8];
      const bf16x8 kf1 = *(const bf16x8*)&kbuf[4096 + (ct * 16 + l16) * 32 + quad * 8];
      const unsigned w0 = *(const unsigned*)(bp + ct * 16);
      const unsigned w1 = *(const unsigned*)(bp + ct * 16 + 2);
      const unsigned x0 = *(const unsigned*)(bp + ct * 16 - 16);
      const unsigned x1 = *(const unsigned*)(bp + ct * 16 - 14);
      const f32x4 c0 = {__builtin_bit_cast(float, w0 << 16),
                        __builtin_bit_cast(float, w0 & 0xFFFF0000u),
                        __builtin_bit_cast(float, w1 << 16),
                        __builtin_bit_cast(float, w1 & 0xFFFF0000u)};
      const f32x4 c1 = {__builtin_bit_cast(float, x0 << 16),
                        __builtin_bit_cast(float, x0 & 0xFFFF0000u),
                        __builtin_bit_cast(float, x1 << 16),
                        __builtin_bit_cast(float, x1 & 0xFFFF0000u)};
      f32x4 s0 = __builtin_amdgcn_mfma_f32_16x16x32_bf16(kf0, qf[0][0], c0, 0, 0, 0);
      s0 = __builtin_amdgcn_mfma_f32_16x16x32_bf16(kf1, qf[0][1], s0, 0, 0, 0);
      f32x4 s1 = __builtin_amdgcn_mfma_f32_16x16x32_bf16(kf0, qf[1][0], c1, 0, 0, 0);
      s1 = __builtin_amdgcn_mfma_f32_16x16x32_bf16(kf1, qf[1][1], s1, 0, 0, 0);
      {
        const float p0 = __builtin_amdgcn_exp2f(s0[0]);
        const float p1 = __builtin_amdgcn_exp2f(s0[1]);
        const float p2 = __builtin_amdgcn_exp2f(s0[2]);
        const float p3 = __builtin_amdgcn_exp2f(s0[3]);
        pk[0][ct][0] = pack2_bf16(p0, p1);
        pk[0][ct][1] = pack2_bf16(p2, p3);
      }
      {
        const float p0 = __builtin_amdgcn_exp2f(s1[0]);
        const float p1 = __builtin_amdgcn_exp2f(s1[1]);
        const float p2 = __builtin_amdgcn_exp2f(s1[2]);
        const float p3 = __builtin_amdgcn_exp2f(s1[3]);
        pk[1][ct][0] = pack2_bf16(p0, p1);
        pk[1][ct][1] = pack2_bf16(p2, p3);
      }
    }

    #pragma unroll
    for (int ct = 0; ct < 8; ++ct) {
      const int gran = ((ct & 1) * 2 + (quad >> 1)) ^ ((l16 & 3) ^ ((l16 >> 2) & 3));
      const int vbase = (ct >> 1) * 2048 + l16 * 32 + gran * 8 + (quad & 1) * 4;
      const s16x4 pf0 = __builtin_bit_cast(s16x4, u32x2{pk[0][ct][0], pk[0][ct][1]});
      const s16x4 pf1 = __builtin_bit_cast(s16x4, u32x2{pk[1][ct][0], pk[1][ct][1]});
      la[0] = __builtin_amdgcn_mfma_f32_16x16x16bf16_1k(ones, pf0, la[0], 0, 0, 0);
      la[1] = __builtin_amdgcn_mfma_f32_16x16x16bf16_1k(ones, pf1, la[1], 0, 0, 0);
      #pragma unroll
      for (int dt = 0; dt < 4; ++dt) {
        const s16x4 vf = *(const s16x4*)&vbuf[vbase + dt * 512];
        o[0][dt] = __builtin_amdgcn_mfma_f32_16x16x16bf16_1k(vf, pf0, o[0][dt], 0, 0, 0);
        o[1][dt] = __builtin_amdgcn_mfma_f32_16x16x16bf16_1k(vf, pf1, o[1][dt], 0, 0, 0);
      }
    }
  }

  const int b = bh >> 3;
  #pragma unroll
  for (int mt = 0; mt < 2; ++mt) {
    const float inv = 1.0f / la[mt][0];
    const int qg = q0 + wave * 32 + mt * 16 + l16;
    __bf16* orow = outb + ((size_t)(b * N_ + qg)) * C_ + h * DH_ + quad * 4;
    #pragma unroll
    for (int dt = 0; dt < 4; ++dt) {
      u32x2 pkd;
      pkd.x = pack2_bf16(o[mt][dt][0] * inv, o[mt][dt][1] * inv);
      pkd.y = pack2_bf16(o[mt][dt][2] * inv, o[mt][dt][3] * inv);
      *(u32x2*)(orow + dt * 16) = pkd;
    }
  }
}

// ---------------- merged fp32 -> bf16 weight cast (4 arrays, 1 launch) --------
__global__ void cast4_kernel(const float* __restrict__ s0, const float* __restrict__ s1,
                             const float* __restrict__ s2, const float* __restrict__ s3,
                             __bf16* __restrict__ d0, __bf16* __restrict__ d1,
                             __bf16* __restrict__ d2, __bf16* __restrict__ d3)
{
  const int i = (blockIdx.x * 256 + threadIdx.x) * 4;
  const float* s; __bf16* d; int off;
  if (i < 786432)       { s = s0; d = d0; off = i; }
  else if (i < 1048576) { s = s1; d = d1; off = i - 786432; }
  else if (i < 2097152) { s = s2; d = d2; off = i - 1048576; }
  else                  { s = s3; d = d3; off = i - 2097152; }
  const float4 v = *(const float4*)(s + off);
  u32x2 pk;
  pk.x = pack2_bf16(v.x, v.y);
  pk.y = pack2_bf16(v.z, v.w);
  *(u32x2*)(d + off) = pk;
}

extern "C" void kernel_launch(void* const* d_in, const int* in_sizes, int n_in,
                              void* d_out, int out_size, void* d_ws, size_t ws_size,
                              hipStream_t stream)
{
  const float* x      = (const float*)d_in[0];
  const float* qkv_w  = (const float*)d_in[1];
  const float* proj_w = (const float*)d_in[2];
  const float* proj_b = (const float*)d_in[3];
  const float* rpb    = (const float*)d_in[4];
  const float* n1w    = (const float*)d_in[5];
  const float* n1b    = (const float*)d_in[6];
  const float* n2w    = (const float*)d_in[7];
  const float* n2b    = (const float*)d_in[8];
  const float* fc1_w  = (const float*)d_in[9];
  const float* fc1_b  = (const float*)d_in[10];
  const float* fc2_w  = (const float*)d_in[11];
  const float* fc2_b  = (const float*)d_in[12];

  char* ws = (char*)d_ws;
  __bf16* hbuf = (__bf16*)(ws + 0);          // 8192*512  bf16
  __bf16* qbuf = (__bf16*)(ws + 8388608);    // [b,h,n,d] (pre-scaled by QSCALE)
  __bf16* kbuf = (__bf16*)(ws + 16777216);   // [b,h,n,d]
  __bf16* vbuf = (__bf16*)(ws + 25165824);   // V^T [b,h,d,n]
  __bf16* gelu = (__bf16*)(ws + 0);          // 8192*2048 bf16 (alias)
  __bf16* wq   = (__bf16*)(ws + 33554432);
  __bf16* wp   = (__bf16*)(ws + 35127296);
  __bf16* w1   = (__bf16*)(ws + 35651584);
  __bf16* w2   = (__bf16*)(ws + 37748736);
  __bf16* attn = (__bf16*)(ws + 39845888);   // 8192*512 bf16
  __bf16* h2in = attn;                       // alias
  float*  x1   = (float*)(ws + 48234496);    // 8192*512 fp32
  float*  outp = (float*)d_out;

  cast4_kernel<<<3072, 256, 0, stream>>>(qkv_w, proj_w, fc1_w, fc2_w, wq, wp, w1, w2);

  ln_kernel<<<2048, 256, 0, stream>>>(x, n1w, n1b, hbuf);

  gemm512<0, 128><<<dim3(64, 12), 512, 0, stream>>>(hbuf, wq, MTOK, 1536, 512,
      nullptr, nullptr, nullptr, nullptr, qbuf, kbuf, vbuf);

  flash_kernel<<<dim3(16, 32), 256, 0, stream>>>(qbuf, kbuf, vbuf, rpb, attn);

  gemm512<1, 64><<<dim3(64, 8), 512, 0, stream>>>(attn, wp, MTOK, 512, 512,
      proj_b, x, x1, nullptr, nullptr, nullptr, nullptr);

  ln_kernel<<<2048, 256, 0, stream>>>(x1, n2w, n2b, h2in);

  gemm512<2, 128><<<dim3(64, 16), 512, 0, stream>>>(h2in, w1, MTOK, 2048, 512,
      fc1_b, nullptr, nullptr, gelu, nullptr, nullptr, nullptr);

  gemm512<1, 64><<<dim3(64, 8), 512, 0, stream>>>(gelu, w2, MTOK, 512, 2048,
      fc2_b, x1, outp, nullptr, nullptr, nullptr, nullptr);
}